// Round 3
// baseline (272.814 us; speedup 1.0000x reference)
//
#include <hip/hip_runtime.h>
#include <math.h>

#define N_NODES 20000
#define N_PAD 20096            // N_NODES rounded up to 128 (GEMM M-tile)
#define N_EDGES 320000
#define IN_CH 512
#define HEADS 4
#define OUT_CH 128
#define HC 512                 // HEADS*OUT_CH
#define NEG_SLOPE 0.2f

// fused-kernel block partitions
#define CVX_BLOCKS 5024        // N_PAD*IN_CH/8/256
#define CVW_BLOCKS 64          // (IN_CH/64)*(HC/64)
#define CNT_BLOCKS 1250        // N_EDGES/256
#define ATT_BLOCKS 1250        // N_NODES/16 (wave per node, 16 waves/block)

typedef __attribute__((ext_vector_type(8))) short short8;
typedef __attribute__((ext_vector_type(4))) float float4v;

// xlb layout: [8 groups][N_PAD][4 heads][16 ch] (bf16)
// group g holds out-channels [g*16, g*16+16) for ALL 4 heads -> 2.56 MB/group,
// L2-resident when group g is pinned to XCD g via blockIdx%8.

// ---------------- edge-index dtype detection (inline, deterministic) ----------------
__device__ __forceinline__ int detect_is64(const int* __restrict__ ei32) {
    int is64 = 1;
    #pragma unroll
    for (int i = 0; i < 32; i++) is64 &= (ei32[2 * i + 1] == 0);
    return is64;
}

__device__ __forceinline__ int edge_at(const void* ei, int is64, long long idx) {
    return is64 ? (int)((const long long*)ei)[idx] : ((const int*)ei)[idx];
}

__device__ __forceinline__ unsigned short f2bf(float f) {
    union { float f; unsigned u; } v; v.f = f;
    unsigned r = v.u + 0x7fffu + ((v.u >> 16) & 1u);   // RNE
    return (unsigned short)(r >> 16);
}

// decode 8 packed bf16 (uint4) -> 8 floats
__device__ __forceinline__ void bf8_decode(uint4 r, float* f) {
    f[0] = __uint_as_float(r.x << 16); f[1] = __uint_as_float(r.x & 0xffff0000u);
    f[2] = __uint_as_float(r.y << 16); f[3] = __uint_as_float(r.y & 0xffff0000u);
    f[4] = __uint_as_float(r.z << 16); f[5] = __uint_as_float(r.z & 0xffff0000u);
    f[6] = __uint_as_float(r.w << 16); f[7] = __uint_as_float(r.w & 0xffff0000u);
}

__device__ __forceinline__ float leaky(float t) { return t > 0.f ? t : NEG_SLOPE * t; }

// ---------------- K1: fused convert_x + convert_w(transpose) + count ----------------
__global__ __launch_bounds__(256) void fusedA_kernel(const float* __restrict__ x,
                                                     const float* __restrict__ W,
                                                     unsigned short* __restrict__ xb,
                                                     unsigned short* __restrict__ Wt,
                                                     const void* __restrict__ ei,
                                                     int* __restrict__ counts) {
    __shared__ float tile[64][65];
    int b = blockIdx.x;
    if (b < CVX_BLOCKS) {
        size_t i = ((size_t)b * 256 + threadIdx.x) * 8;
        unsigned short o[8];
        if (i < (size_t)N_NODES * IN_CH) {
            float4 f0 = *(const float4*)&x[i];
            float4 f1 = *(const float4*)&x[i + 4];
            o[0] = f2bf(f0.x); o[1] = f2bf(f0.y); o[2] = f2bf(f0.z); o[3] = f2bf(f0.w);
            o[4] = f2bf(f1.x); o[5] = f2bf(f1.y); o[6] = f2bf(f1.z); o[7] = f2bf(f1.w);
        } else {
            for (int k = 0; k < 8; k++) o[k] = 0;
        }
        *(short8*)&xb[i] = *(short8*)o;
    } else if (b < CVX_BLOCKS + CVW_BLOCKS) {
        int idx = b - CVX_BLOCKS;
        int k0 = (idx & 7) * 64, n0 = (idx >> 3) * 64;
        int t = threadIdx.x, r = t >> 6, c = t & 63;
        for (int rr = r; rr < 64; rr += 4)
            tile[rr][c] = W[(size_t)(k0 + rr) * HC + n0 + c];
        __syncthreads();
        for (int rr = r; rr < 64; rr += 4)
            Wt[(size_t)(n0 + rr) * IN_CH + k0 + c] = f2bf(tile[c][rr]);
    } else {
        int is64 = detect_is64((const int*)ei);
        int e = (b - CVX_BLOCKS - CVW_BLOCKS) * 256 + threadIdx.x;
        if (e < N_EDGES) {
            int dst = edge_at(ei, is64, (long long)N_EDGES + e);
            atomicAdd(&counts[dst], 1);
        }
    }
}

// ---------------- bf16 MFMA GEMM: xlb[g][M][h][16](bf16) = A[M,K] @ Wt[N,K]^T ----------------
__global__ __launch_bounds__(256) void gemm_kernel(const unsigned short* __restrict__ A,
                                                   const unsigned short* __restrict__ Bt,
                                                   unsigned short* __restrict__ Cb) {
    __shared__ __align__(16) unsigned short As[128 * 32];
    __shared__ __align__(16) unsigned short Bs[128 * 32];
    const int bm = blockIdx.y * 128;
    const int bn = blockIdx.x * 128;
    const int t = threadIdx.x;
    const int wv = t >> 6, lane = t & 63;
    const int wm = wv & 1, wn = wv >> 1;
    const int lm = lane & 15, lk = lane >> 4;

    float4v acc[4][4];
    #pragma unroll
    for (int i = 0; i < 4; i++)
        #pragma unroll
        for (int j = 0; j < 4; j++) acc[i][j] = (float4v){0.f, 0.f, 0.f, 0.f};

    const int srow = t >> 2;
    const int skof = (t & 3) * 8;

    for (int k0 = 0; k0 < IN_CH; k0 += 32) {
        __syncthreads();
        #pragma unroll
        for (int q = 0; q < 2; q++) {
            const unsigned short* gA = A + (size_t)(bm + q * 64 + srow) * IN_CH + k0 + skof;
            const unsigned short* gB = Bt + (size_t)(bn + q * 64 + srow) * IN_CH + k0 + skof;
            __builtin_amdgcn_global_load_lds((const __attribute__((address_space(1))) void*)gA,
                                             (__attribute__((address_space(3))) void*)&As[q * 2048 + t * 8], 16, 0, 0);
            __builtin_amdgcn_global_load_lds((const __attribute__((address_space(1))) void*)gB,
                                             (__attribute__((address_space(3))) void*)&Bs[q * 2048 + t * 8], 16, 0, 0);
        }
        __syncthreads();

        short8 af[4], bf[4];
        #pragma unroll
        for (int i = 0; i < 4; i++)
            af[i] = *(const short8*)&As[(wm * 64 + i * 16 + lm) * 32 + lk * 8];
        #pragma unroll
        for (int j = 0; j < 4; j++)
            bf[j] = *(const short8*)&Bs[(wn * 64 + j * 16 + lm) * 32 + lk * 8];
        #pragma unroll
        for (int i = 0; i < 4; i++)
            #pragma unroll
            for (int j = 0; j < 4; j++)
                acc[i][j] = __builtin_amdgcn_mfma_f32_16x16x32_bf16(af[i], bf[j], acc[i][j], 0, 0, 0);
    }

    // store into grouped layout: col = bn + wn*64 + j*16 + lm
    //   head h = bn>>7 (bn is a multiple of 128, wn*64+j*16+lm < 128)
    //   group g = (wn*64 + j*16)>>4 = wn*4 + j;  within-group ch = lm
    const int h = bn >> 7;
    #pragma unroll
    for (int i = 0; i < 4; i++) {
        #pragma unroll
        for (int r = 0; r < 4; r++) {
            int row = bm + wm * 64 + i * 16 + lk * 4 + r;
            if (row < N_NODES) {
                #pragma unroll
                for (int j = 0; j < 4; j++) {
                    int g = wn * 4 + j;
                    Cb[((size_t)g * N_PAD + row) * 64 + h * 16 + lm] = f2bf(acc[i][j][r]);
                }
            }
        }
    }
}

// ---------------- K3: fused scan (block 0) + attention halves (blocks 1..) ----------------
__global__ __launch_bounds__(1024) void scanattn_kernel(const int* __restrict__ counts,
                                                        int* __restrict__ offsets,
                                                        const unsigned short* __restrict__ xlb,
                                                        const float* __restrict__ att_s,
                                                        const float* __restrict__ att_d,
                                                        float* __restrict__ a_s,
                                                        float* __restrict__ a_d) {
    int b = blockIdx.x;
    if (b == 0) {
        // chunked exclusive scan: counts -> offsets
        const int CHUNK = 20;                 // 1024*20 = 20480 >= N_NODES
        int tid = threadIdx.x;
        int base = tid * CHUNK;
        int c[CHUNK];
        #pragma unroll
        for (int k = 0; k < CHUNK; k++) {
            int i = base + k;
            c[k] = (i < N_NODES) ? counts[i] : 0;
        }
        int pre[CHUNK];
        int sum = 0;
        #pragma unroll
        for (int k = 0; k < CHUNK; k++) { pre[k] = sum; sum += c[k]; }

        int lane = tid & 63, wvv = tid >> 6;
        int s = sum;
        #pragma unroll
        for (int off = 1; off < 64; off <<= 1) {
            int u = __shfl_up(s, off, 64);
            if (lane >= off) s += u;
        }
        __shared__ int wsum[16];
        if (lane == 63) wsum[wvv] = s;
        __syncthreads();
        if (tid < 16) {
            int u = wsum[tid];
            #pragma unroll
            for (int off = 1; off < 16; off <<= 1) {
                int w = __shfl_up(u, off, 64);
                if (tid >= off) u += w;
            }
            wsum[tid] = u;
        }
        __syncthreads();
        int wbase = (wvv == 0) ? 0 : wsum[wvv - 1];
        int excl = wbase + s - sum;
        #pragma unroll
        for (int k = 0; k < CHUNK; k++) {
            int i = base + k;
            if (i < N_NODES) offsets[i] = excl + pre[k];
        }
        if (tid == 1023) offsets[N_NODES] = wbase + s;
    } else {
        // a_s[n,h], a_d[n,h] — wave per node, 16 nodes per 1024-thread block
        // lane owns original cols lane*8..lane*8+7; read from grouped layout:
        //   h = lane>>4, g = (lane&15)>>1, sub16 = (lane&1)*8
        int node = (b - 1) * 16 + (threadIdx.x >> 6);
        if (node >= N_NODES) return;
        int lane = threadIdx.x & 63;
        int hd = lane >> 4;
        int g2 = (lane & 15) >> 1;
        uint4 r = *(const uint4*)&xlb[((size_t)g2 * N_PAD + node) * 64 + hd * 16 + (lane & 1) * 8];
        float f[8];
        bf8_decode(r, f);
        float4 s0 = *(const float4*)&att_s[lane * 8];
        float4 s1 = *(const float4*)&att_s[lane * 8 + 4];
        float4 d0 = *(const float4*)&att_d[lane * 8];
        float4 d1 = *(const float4*)&att_d[lane * 8 + 4];
        float s = f[0]*s0.x + f[1]*s0.y + f[2]*s0.z + f[3]*s0.w
                + f[4]*s1.x + f[5]*s1.y + f[6]*s1.z + f[7]*s1.w;
        float d = f[0]*d0.x + f[1]*d0.y + f[2]*d0.z + f[3]*d0.w
                + f[4]*d1.x + f[5]*d1.y + f[6]*d1.z + f[7]*d1.w;
        #pragma unroll
        for (int off = 1; off < 16; off <<= 1) {
            s += __shfl_xor(s, off, 64);
            d += __shfl_xor(d, off, 64);
        }
        if ((lane & 15) == 0) {
            a_s[node * 4 + hd] = s;
            a_d[node * 4 + hd] = d;
        }
    }
}

// ---------------- K4: scatter (CSR bucketing only; weights recomputed in gather) ----------------
__global__ __launch_bounds__(256) void scatterw_kernel(const void* __restrict__ ei,
                                                       const int* __restrict__ offsets,
                                                       int* __restrict__ cursor,
                                                       int* __restrict__ sorted_src) {
    int is64 = detect_is64((const int*)ei);
    int e = blockIdx.x * 256 + threadIdx.x;
    if (e < N_EDGES) {
        int dst = edge_at(ei, is64, (long long)N_EDGES + e);
        int src = edge_at(ei, is64, e);
        int pos = offsets[dst] + atomicAdd(&cursor[dst], 1);
        sorted_src[pos] = src;
    }
}

// ---------------- segment softmax + weighted gather (channel-grouped, XCD-pinned) ----------------
// Block bid: group g = bid&7 (pinned to XCD g via round-robin dispatch), node quad q = bid>>3.
// One wave per node: 8 edge slots x 8 lanes/slot; lane covers 8 channels (16 B) of its
// (head = (lane&7)>>1, half = lane&1) sub-slice. Group slice = 2.56 MB -> L2-resident.
// Weights recomputed from L2-resident a_s/a_d (no max subtraction; logits bounded).
__global__ __launch_bounds__(256) void gather_kernel(const unsigned short* __restrict__ xlb,
                                                     const float* __restrict__ a_s,
                                                     const float* __restrict__ a_d,
                                                     const int* __restrict__ offsets,
                                                     const int* __restrict__ sorted_src,
                                                     const float* __restrict__ bias,
                                                     float* __restrict__ out) {
    int g    = blockIdx.x & 7;
    int q    = blockIdx.x >> 3;
    int wv   = threadIdx.x >> 6;
    int node = q * 4 + wv;              // q < 5000 -> node < 20000 always
    int lane = threadIdx.x & 63;
    int slot = lane >> 3;               // 8 edge slots per wave
    int sub  = lane & 7;
    int h    = sub >> 1;                // head 0..3
    int cp   = sub & 1;                 // which 8-ch half of the 16-ch group

    const unsigned short* xg = xlb + ((size_t)g * N_PAD) * 64 + h * 16 + cp * 8;
    float ad = a_d[node * 4 + h];
    int beg = offsets[node], end = offsets[node + 1];

    float acc[8] = {0, 0, 0, 0, 0, 0, 0, 0};
    float denom = 0.f;

    if (slot == 0) {   // self-loop
        float w = __expf(leaky(a_s[node * 4 + h] + ad));
        denom = w;
        uint4 r = *(const uint4*)(xg + (size_t)node * 64);
        float f[8];
        bf8_decode(r, f);
        #pragma unroll
        for (int k = 0; k < 8; k++) acc[k] = w * f[k];
    }

    for (int e = beg + slot; e < end; e += 8) {
        int s = sorted_src[e];
        float w = __expf(leaky(a_s[s * 4 + h] + ad));
        uint4 r = *(const uint4*)(xg + (size_t)s * 64);
        denom += w;
        float f[8];
        bf8_decode(r, f);
        #pragma unroll
        for (int k = 0; k < 8; k++) acc[k] += w * f[k];
    }

    // reduce across the 8 edge slots (lane bits 3..5)
    #pragma unroll
    for (int off = 8; off < 64; off <<= 1) {
        denom += __shfl_xor(denom, off, 64);
        #pragma unroll
        for (int k = 0; k < 8; k++) acc[k] += __shfl_xor(acc[k], off, 64);
    }

    // per-head normalize (fold 1/4 head-mean in), then sum heads (lane bits 1..2)
    float rd = 0.25f / (denom + 1e-16f);
    float v[8];
    #pragma unroll
    for (int k = 0; k < 8; k++) {
        float t = acc[k] * rd;
        t += __shfl_xor(t, 2, 64);
        t += __shfl_xor(t, 4, 64);
        v[k] = t;
    }

    if (lane < 2) {                     // lanes 0,1: cp = 0,1 hold the full head-sum
        int cbase = g * 16 + cp * 8;
        float o[8];
        #pragma unroll
        for (int k = 0; k < 8; k++) {
            float t = v[k] + bias[cbase + k];
            o[k] = t > 0.f ? t : expm1f(t);
        }
        *(float4*)&out[(size_t)node * OUT_CH + cbase]     = make_float4(o[0], o[1], o[2], o[3]);
        *(float4*)&out[(size_t)node * OUT_CH + cbase + 4] = make_float4(o[4], o[5], o[6], o[7]);
    }
}

// ---------------- launch ----------------
extern "C" void kernel_launch(void* const* d_in, const int* in_sizes, int n_in,
                              void* d_out, int out_size, void* d_ws, size_t ws_size,
                              hipStream_t stream) {
    const float* x       = (const float*)d_in[0];
    const float* W       = (const float*)d_in[1];
    const float* att_src = (const float*)d_in[2];
    const float* att_dst = (const float*)d_in[3];
    const float* bias    = (const float*)d_in[4];
    const void*  ei      = d_in[5];
    float* out = (float*)d_out;

    char* ws = (char*)d_ws;
    size_t off = 0;
    unsigned short* xlb = (unsigned short*)(ws + off); off += (size_t)N_PAD * HC * sizeof(unsigned short);
    float* a_s     = (float*)(ws + off); off += (size_t)N_NODES * HEADS * sizeof(float);
    float* a_d     = (float*)(ws + off); off += (size_t)N_NODES * HEADS * sizeof(float);
    int* counts    = (int*)(ws + off);   off += (size_t)N_NODES * sizeof(int);
    int* cursor    = (int*)(ws + off);   off += (size_t)N_NODES * sizeof(int);   // contiguous with counts
    int* offsets   = (int*)(ws + off);   off += (size_t)(N_NODES + 1) * sizeof(int);
    off = (off + 15) & ~(size_t)15;
    int* sorted_src = (int*)(ws + off);  off += (size_t)N_EDGES * sizeof(int);
    off = (off + 15) & ~(size_t)15;
    unsigned short* xb = (unsigned short*)(ws + off); off += (size_t)N_PAD * IN_CH * sizeof(unsigned short);
    unsigned short* Wt = (unsigned short*)(ws + off); off += (size_t)IN_CH * HC * sizeof(unsigned short);

    hipMemsetAsync(counts, 0, 2u * N_NODES * sizeof(int), stream);   // counts + cursor
    fusedA_kernel<<<CVX_BLOCKS + CVW_BLOCKS + CNT_BLOCKS, 256, 0, stream>>>(x, W, xb, Wt, ei, counts);
    gemm_kernel<<<dim3(HC / 128, N_PAD / 128), 256, 0, stream>>>(xb, Wt, xlb);
    scanattn_kernel<<<1 + ATT_BLOCKS, 1024, 0, stream>>>(counts, offsets, xlb, att_src, att_dst, a_s, a_d);
    scatterw_kernel<<<(N_EDGES + 255) / 256, 256, 0, stream>>>(ei, offsets, cursor, sorted_src);
    gather_kernel<<<(N_NODES / 4) * 8, 256, 0, stream>>>(xlb, a_s, a_d, offsets, sorted_src, bias, out);
}

// Round 4
// 220.173 us; speedup vs baseline: 1.2391x; 1.2391x over previous
//
#include <hip/hip_runtime.h>
#include <math.h>

#define N_NODES 20000
#define N_PAD 20096            // N_NODES rounded up to 128 (GEMM M-tile)
#define N_EDGES 320000
#define IN_CH 512
#define HEADS 4
#define OUT_CH 128
#define HC 512                 // HEADS*OUT_CH
#define NEG_SLOPE 0.2f

// fused-kernel block partitions
#define CVX_BLOCKS 5024        // N_PAD*IN_CH/8/256
#define CVW_BLOCKS 64          // (IN_CH/64)*(HC/64)
#define CNT_BLOCKS 1250        // N_EDGES/256

typedef __attribute__((ext_vector_type(8))) short short8;
typedef __attribute__((ext_vector_type(4))) float float4v;

// ---------------- edge-index dtype detection (inline, deterministic) ----------------
__device__ __forceinline__ int detect_is64(const int* __restrict__ ei32) {
    int is64 = 1;
    #pragma unroll
    for (int i = 0; i < 32; i++) is64 &= (ei32[2 * i + 1] == 0);
    return is64;
}

__device__ __forceinline__ int edge_at(const void* ei, int is64, long long idx) {
    return is64 ? (int)((const long long*)ei)[idx] : ((const int*)ei)[idx];
}

__device__ __forceinline__ unsigned short f2bf(float f) {
    union { float f; unsigned u; } v; v.f = f;
    unsigned r = v.u + 0x7fffu + ((v.u >> 16) & 1u);   // RNE
    return (unsigned short)(r >> 16);
}

// decode 8 packed bf16 (uint4) -> 8 floats
__device__ __forceinline__ void bf8_decode(uint4 r, float* f) {
    f[0] = __uint_as_float(r.x << 16); f[1] = __uint_as_float(r.x & 0xffff0000u);
    f[2] = __uint_as_float(r.y << 16); f[3] = __uint_as_float(r.y & 0xffff0000u);
    f[4] = __uint_as_float(r.z << 16); f[5] = __uint_as_float(r.z & 0xffff0000u);
    f[6] = __uint_as_float(r.w << 16); f[7] = __uint_as_float(r.w & 0xffff0000u);
}

__device__ __forceinline__ float leaky(float t) { return t > 0.f ? t : NEG_SLOPE * t; }

// pick w[hd] from a float4 of per-head weights (hd in 0..3) without scratch
__device__ __forceinline__ float sel_head(float4 w, int hd) {
    float lo = (hd & 1) ? w.y : w.x;
    float hi = (hd & 1) ? w.w : w.z;
    return (hd & 2) ? hi : lo;
}

// ---------------- K1: fused convert_x + convert_w(transpose) + count(+epos) ----------------
__global__ __launch_bounds__(256) void fusedA_kernel(const float* __restrict__ x,
                                                     const float* __restrict__ W,
                                                     unsigned short* __restrict__ xb,
                                                     unsigned short* __restrict__ Wt,
                                                     const void* __restrict__ ei,
                                                     int* __restrict__ counts,
                                                     int* __restrict__ epos) {
    __shared__ float tile[64][65];
    int b = blockIdx.x;
    if (b < CVX_BLOCKS) {
        size_t i = ((size_t)b * 256 + threadIdx.x) * 8;
        unsigned short o[8];
        if (i < (size_t)N_NODES * IN_CH) {
            float4 f0 = *(const float4*)&x[i];
            float4 f1 = *(const float4*)&x[i + 4];
            o[0] = f2bf(f0.x); o[1] = f2bf(f0.y); o[2] = f2bf(f0.z); o[3] = f2bf(f0.w);
            o[4] = f2bf(f1.x); o[5] = f2bf(f1.y); o[6] = f2bf(f1.z); o[7] = f2bf(f1.w);
        } else {
            for (int k = 0; k < 8; k++) o[k] = 0;
        }
        *(short8*)&xb[i] = *(short8*)o;
    } else if (b < CVX_BLOCKS + CVW_BLOCKS) {
        int idx = b - CVX_BLOCKS;
        int k0 = (idx & 7) * 64, n0 = (idx >> 3) * 64;
        int t = threadIdx.x, r = t >> 6, c = t & 63;
        for (int rr = r; rr < 64; rr += 4)
            tile[rr][c] = W[(size_t)(k0 + rr) * HC + n0 + c];
        __syncthreads();
        for (int rr = r; rr < 64; rr += 4)
            Wt[(size_t)(n0 + rr) * IN_CH + k0 + c] = f2bf(tile[c][rr]);
    } else {
        int is64 = detect_is64((const int*)ei);
        int e = (b - CVX_BLOCKS - CVW_BLOCKS) * 256 + threadIdx.x;
        if (e < N_EDGES) {
            int dst = edge_at(ei, is64, (long long)N_EDGES + e);
            int p = atomicAdd(&counts[dst], 1);
            epos[e] = p;                 // position within dst's segment (no 2nd atomic later)
        }
    }
}

// ---------------- bf16 MFMA GEMM + fused a_s/a_d epilogue ----------------
// xlb[M,HC](bf16) = A[M,K] @ Wt[N,K]^T ; block col-tile bn covers exactly head h=bn>>7,
// so a_s[row,h]=dot(xl[row,h*128:+128],att_src[h]) is block-local: computed from fp32 acc.
__global__ __launch_bounds__(256) void gemm_kernel(const unsigned short* __restrict__ A,
                                                   const unsigned short* __restrict__ Bt,
                                                   unsigned short* __restrict__ Cb,
                                                   const float* __restrict__ att_s,
                                                   const float* __restrict__ att_d,
                                                   float* __restrict__ a_s,
                                                   float* __restrict__ a_d) {
    __shared__ __align__(16) unsigned short As[128 * 32];
    __shared__ __align__(16) unsigned short Bs[128 * 32];
    __shared__ float ssum[128][2];
    __shared__ float dsum[128][2];
    const int bm = blockIdx.y * 128;
    const int bn = blockIdx.x * 128;
    const int t = threadIdx.x;
    const int wv = t >> 6, lane = t & 63;
    const int wm = wv & 1, wn = wv >> 1;
    const int lm = lane & 15, lk = lane >> 4;

    float4v acc[4][4];
    #pragma unroll
    for (int i = 0; i < 4; i++)
        #pragma unroll
        for (int j = 0; j < 4; j++) acc[i][j] = (float4v){0.f, 0.f, 0.f, 0.f};

    const int srow = t >> 2;
    const int skof = (t & 3) * 8;

    for (int k0 = 0; k0 < IN_CH; k0 += 32) {
        __syncthreads();
        #pragma unroll
        for (int q = 0; q < 2; q++) {
            const unsigned short* gA = A + (size_t)(bm + q * 64 + srow) * IN_CH + k0 + skof;
            const unsigned short* gB = Bt + (size_t)(bn + q * 64 + srow) * IN_CH + k0 + skof;
            __builtin_amdgcn_global_load_lds((const __attribute__((address_space(1))) void*)gA,
                                             (__attribute__((address_space(3))) void*)&As[q * 2048 + t * 8], 16, 0, 0);
            __builtin_amdgcn_global_load_lds((const __attribute__((address_space(1))) void*)gB,
                                             (__attribute__((address_space(3))) void*)&Bs[q * 2048 + t * 8], 16, 0, 0);
        }
        __syncthreads();

        short8 af[4], bf[4];
        #pragma unroll
        for (int i = 0; i < 4; i++)
            af[i] = *(const short8*)&As[(wm * 64 + i * 16 + lm) * 32 + lk * 8];
        #pragma unroll
        for (int j = 0; j < 4; j++)
            bf[j] = *(const short8*)&Bs[(wn * 64 + j * 16 + lm) * 32 + lk * 8];
        #pragma unroll
        for (int i = 0; i < 4; i++)
            #pragma unroll
            for (int j = 0; j < 4; j++)
                acc[i][j] = __builtin_amdgcn_mfma_f32_16x16x32_bf16(af[i], bf[j], acc[i][j], 0, 0, 0);
    }

    // C store (flat [row][col] bf16)
    #pragma unroll
    for (int i = 0; i < 4; i++) {
        #pragma unroll
        for (int r = 0; r < 4; r++) {
            int row = bm + wm * 64 + i * 16 + lk * 4 + r;
            if (row < N_NODES) {
                #pragma unroll
                for (int j = 0; j < 4; j++) {
                    int col = bn + wn * 64 + j * 16 + lm;
                    Cb[(size_t)row * HC + col] = f2bf(acc[i][j][r]);
                }
            }
        }
    }

    // ---- attention-half epilogue: a_s/a_d for this block's 128 rows, head h ----
    const int h = bn >> 7;
    float as_w[4], ad_w[4];
    #pragma unroll
    for (int j = 0; j < 4; j++) {
        int col = bn + wn * 64 + j * 16 + lm;      // flat index into [4][128] att arrays
        as_w[j] = att_s[col];
        ad_w[j] = att_d[col];
    }
    float ps[4][4], pd[4][4];
    #pragma unroll
    for (int i = 0; i < 4; i++)
        #pragma unroll
        for (int r = 0; r < 4; r++) {
            float s = 0.f, d = 0.f;
            #pragma unroll
            for (int j = 0; j < 4; j++) { s += acc[i][j][r] * as_w[j]; d += acc[i][j][r] * ad_w[j]; }
            ps[i][r] = s; pd[i][r] = d;
        }
    #pragma unroll
    for (int off = 1; off < 16; off <<= 1) {
        #pragma unroll
        for (int i = 0; i < 4; i++)
            #pragma unroll
            for (int r = 0; r < 4; r++) {
                ps[i][r] += __shfl_xor(ps[i][r], off, 64);
                pd[i][r] += __shfl_xor(pd[i][r], off, 64);
            }
    }
    if (lm == 0) {
        #pragma unroll
        for (int i = 0; i < 4; i++)
            #pragma unroll
            for (int r = 0; r < 4; r++) {
                int rl = wm * 64 + i * 16 + lk * 4 + r;
                ssum[rl][wn] = ps[i][r];
                dsum[rl][wn] = pd[i][r];
            }
    }
    __syncthreads();
    if (t < 128) {
        int row = bm + t;
        if (row < N_NODES) {
            a_s[row * 4 + h] = ssum[t][0] + ssum[t][1];
            a_d[row * 4 + h] = dsum[t][0] + dsum[t][1];
        }
    }
}

// ---------------- K3: exclusive scan counts -> offsets (single block) ----------------
__global__ __launch_bounds__(1024) void scan_kernel(const int* __restrict__ counts,
                                                    int* __restrict__ offsets) {
    const int CHUNK = 20;                 // 1024*20 = 20480 >= N_NODES
    int tid = threadIdx.x;
    int base = tid * CHUNK;
    int c[CHUNK];
    #pragma unroll
    for (int k = 0; k < CHUNK; k++) {
        int i = base + k;
        c[k] = (i < N_NODES) ? counts[i] : 0;
    }
    int pre[CHUNK];
    int sum = 0;
    #pragma unroll
    for (int k = 0; k < CHUNK; k++) { pre[k] = sum; sum += c[k]; }

    int lane = tid & 63, wvv = tid >> 6;
    int s = sum;
    #pragma unroll
    for (int off = 1; off < 64; off <<= 1) {
        int u = __shfl_up(s, off, 64);
        if (lane >= off) s += u;
    }
    __shared__ int wsum[16];
    if (lane == 63) wsum[wvv] = s;
    __syncthreads();
    if (tid < 16) {
        int u = wsum[tid];
        #pragma unroll
        for (int off = 1; off < 16; off <<= 1) {
            int w = __shfl_up(u, off, 64);
            if (tid >= off) u += w;
        }
        wsum[tid] = u;
    }
    __syncthreads();
    int wbase = (wvv == 0) ? 0 : wsum[wvv - 1];
    int excl = wbase + s - sum;
    #pragma unroll
    for (int k = 0; k < CHUNK; k++) {
        int i = base + k;
        if (i < N_NODES) offsets[i] = excl + pre[k];
    }
    if (tid == 1023) offsets[N_NODES] = wbase + s;
}

// ---------------- K4: scatter + per-edge weights (no atomics — epos precomputed) ----------------
__global__ __launch_bounds__(256) void scatterw_kernel(const void* __restrict__ ei,
                                                       const int* __restrict__ offsets,
                                                       const int* __restrict__ epos,
                                                       int* __restrict__ sorted_src,
                                                       const float* __restrict__ a_s,
                                                       const float* __restrict__ a_d,
                                                       float* __restrict__ edge_w) {
    int is64 = detect_is64((const int*)ei);
    int e = blockIdx.x * 256 + threadIdx.x;
    if (e < N_EDGES) {
        int dst = edge_at(ei, is64, (long long)N_EDGES + e);
        int src = edge_at(ei, is64, e);
        int pos = offsets[dst] + epos[e];
        sorted_src[pos] = src;
        float4 as4 = *(const float4*)&a_s[src * 4];
        float4 ad4 = *(const float4*)&a_d[dst * 4];
        float4 w;
        w.x = __expf(leaky(as4.x + ad4.x));
        w.y = __expf(leaky(as4.y + ad4.y));
        w.z = __expf(leaky(as4.z + ad4.z));
        w.w = __expf(leaky(as4.w + ad4.w));
        *(float4*)&edge_w[(size_t)pos * 4] = w;
    }
}

// ---------------- segment softmax + weighted gather ----------------
// 4 waves per node (stride-16, 4-edge chunks each), partials combined via LDS.
// No max subtraction (logits bounded; fp32 exp safe; algebraically identical).
// Lane owns channels lane*8..+7 => head = lane>>4. Indices/weights wave-uniform.
__global__ __launch_bounds__(256) void gather_kernel(const unsigned short* __restrict__ xlb,
                                                     const float* __restrict__ a_s,
                                                     const float* __restrict__ a_d,
                                                     const int* __restrict__ offsets,
                                                     const int* __restrict__ sorted_src,
                                                     const float* __restrict__ edge_w,
                                                     const float* __restrict__ bias,
                                                     float* __restrict__ out) {
    __shared__ float cl[3][64][9];
    int sub = threadIdx.x >> 6;         // wave 0..3 of this node
    int node = blockIdx.x;              // grid = N_NODES
    int lane = threadIdx.x & 63;
    int hd = lane >> 4;
    int beg = offsets[node], end = offsets[node + 1];

    const unsigned short* xrow = xlb + lane * 8;
    float acc[8] = {0, 0, 0, 0, 0, 0, 0, 0};
    float denom = 0.f;

    if (sub == 0) {   // self-loop
        float4 as4 = *(const float4*)&a_s[node * 4];
        float4 ad4 = *(const float4*)&a_d[node * 4];
        float4 ws;
        ws.x = __expf(leaky(as4.x + ad4.x));
        ws.y = __expf(leaky(as4.y + ad4.y));
        ws.z = __expf(leaky(as4.z + ad4.z));
        ws.w = __expf(leaky(as4.w + ad4.w));
        float w = sel_head(ws, hd);
        denom = w;
        uint4 r = *(const uint4*)(xrow + (size_t)node * HC);
        float f[8];
        bf8_decode(r, f);
        #pragma unroll
        for (int k = 0; k < 8; k++) acc[k] = w * f[k];
    }

    for (int c0 = beg + sub * 4; c0 < end; c0 += 16) {
        int n = end - c0;
        if (n >= 4) {
            int s0 = sorted_src[c0];
            int s1 = sorted_src[c0 + 1];
            int s2 = sorted_src[c0 + 2];
            int s3 = sorted_src[c0 + 3];
            uint4 r0 = *(const uint4*)(xrow + (size_t)s0 * HC);
            uint4 r1 = *(const uint4*)(xrow + (size_t)s1 * HC);
            uint4 r2 = *(const uint4*)(xrow + (size_t)s2 * HC);
            uint4 r3 = *(const uint4*)(xrow + (size_t)s3 * HC);
            float4 wa = *(const float4*)&edge_w[(size_t)c0 * 4];
            float4 wb = *(const float4*)&edge_w[(size_t)(c0 + 1) * 4];
            float4 wc = *(const float4*)&edge_w[(size_t)(c0 + 2) * 4];
            float4 wd = *(const float4*)&edge_w[(size_t)(c0 + 3) * 4];
            float w0 = sel_head(wa, hd), w1 = sel_head(wb, hd);
            float w2 = sel_head(wc, hd), w3 = sel_head(wd, hd);
            denom += (w0 + w1) + (w2 + w3);
            float f0[8], f1[8], f2[8], f3[8];
            bf8_decode(r0, f0);
            bf8_decode(r1, f1);
            bf8_decode(r2, f2);
            bf8_decode(r3, f3);
            #pragma unroll
            for (int k = 0; k < 8; k++)
                acc[k] += (w0 * f0[k] + w1 * f1[k]) + (w2 * f2[k] + w3 * f3[k]);
        } else {
            for (int j = 0; j < n; j++) {
                int s0 = sorted_src[c0 + j];
                uint4 r0 = *(const uint4*)(xrow + (size_t)s0 * HC);
                float4 wa = *(const float4*)&edge_w[(size_t)(c0 + j) * 4];
                float w0 = sel_head(wa, hd);
                denom += w0;
                float f0[8];
                bf8_decode(r0, f0);
                #pragma unroll
                for (int k = 0; k < 8; k++) acc[k] += w0 * f0[k];
            }
        }
    }

    if (sub != 0) {
        #pragma unroll
        for (int k = 0; k < 8; k++) cl[sub - 1][lane][k] = acc[k];
        cl[sub - 1][lane][8] = denom;
    }
    __syncthreads();
    if (sub == 0) {
        #pragma unroll
        for (int p = 0; p < 3; p++) {
            #pragma unroll
            for (int k = 0; k < 8; k++) acc[k] += cl[p][lane][k];
            denom += cl[p][lane][8];
        }

        float rd = 0.25f / (denom + 1e-16f);   // fold head-mean into normalize
        float v[8];
        #pragma unroll
        for (int k = 0; k < 8; k++) {
            float t = acc[k] * rd;
            t += __shfl_xor(t, 16, 64);
            t += __shfl_xor(t, 32, 64);
            v[k] = t;
        }
        if (hd == 0) {
            float4 b0 = *(const float4*)&bias[lane * 8];
            float4 b1 = *(const float4*)&bias[lane * 8 + 4];
            float o[8];
            o[0] = v[0] + b0.x; o[1] = v[1] + b0.y; o[2] = v[2] + b0.z; o[3] = v[3] + b0.w;
            o[4] = v[4] + b1.x; o[5] = v[5] + b1.y; o[6] = v[6] + b1.z; o[7] = v[7] + b1.w;
            #pragma unroll
            for (int k = 0; k < 8; k++) o[k] = o[k] > 0.f ? o[k] : expm1f(o[k]);
            *(float4*)&out[(size_t)node * OUT_CH + lane * 8]     = make_float4(o[0], o[1], o[2], o[3]);
            *(float4*)&out[(size_t)node * OUT_CH + lane * 8 + 4] = make_float4(o[4], o[5], o[6], o[7]);
        }
    }
}

// ---------------- launch ----------------
extern "C" void kernel_launch(void* const* d_in, const int* in_sizes, int n_in,
                              void* d_out, int out_size, void* d_ws, size_t ws_size,
                              hipStream_t stream) {
    const float* x       = (const float*)d_in[0];
    const float* W       = (const float*)d_in[1];
    const float* att_src = (const float*)d_in[2];
    const float* att_dst = (const float*)d_in[3];
    const float* bias    = (const float*)d_in[4];
    const void*  ei      = d_in[5];
    float* out = (float*)d_out;

    char* ws = (char*)d_ws;
    size_t off = 0;
    unsigned short* xlb = (unsigned short*)(ws + off); off += (size_t)N_PAD * HC * sizeof(unsigned short);
    float* a_s     = (float*)(ws + off); off += (size_t)N_NODES * HEADS * sizeof(float);
    float* a_d     = (float*)(ws + off); off += (size_t)N_NODES * HEADS * sizeof(float);
    int* counts    = (int*)(ws + off);   off += (size_t)N_NODES * sizeof(int);
    int* offsets   = (int*)(ws + off);   off += (size_t)(N_NODES + 1) * sizeof(int);
    off = (off + 15) & ~(size_t)15;
    int* epos      = (int*)(ws + off);   off += (size_t)N_EDGES * sizeof(int);
    int* sorted_src = (int*)(ws + off);  off += (size_t)N_EDGES * sizeof(int);
    off = (off + 15) & ~(size_t)15;
    float* edge_w  = (float*)(ws + off); off += (size_t)N_EDGES * HEADS * sizeof(float);
    unsigned short* xb = (unsigned short*)(ws + off); off += (size_t)N_PAD * IN_CH * sizeof(unsigned short);
    unsigned short* Wt = (unsigned short*)(ws + off); off += (size_t)IN_CH * HC * sizeof(unsigned short);

    hipMemsetAsync(counts, 0, N_NODES * sizeof(int), stream);
    fusedA_kernel<<<CVX_BLOCKS + CVW_BLOCKS + CNT_BLOCKS, 256, 0, stream>>>(x, W, xb, Wt, ei, counts, epos);
    gemm_kernel<<<dim3(HC / 128, N_PAD / 128), 256, 0, stream>>>(xb, Wt, xlb, att_src, att_dst, a_s, a_d);
    scan_kernel<<<1, 1024, 0, stream>>>(counts, offsets);
    scatterw_kernel<<<(N_EDGES + 255) / 256, 256, 0, stream>>>(ei, offsets, epos, sorted_src, a_s, a_d, edge_w);
    gather_kernel<<<N_NODES, 256, 0, stream>>>(xlb, a_s, a_d, offsets, sorted_src, edge_w, bias, out);
}

// Round 5
// 214.286 us; speedup vs baseline: 1.2731x; 1.0275x over previous
//
#include <hip/hip_runtime.h>
#include <math.h>

#define N_NODES 20000
#define N_PAD 20096            // N_NODES rounded up to 128 (GEMM M-tile)
#define N_EDGES 320000
#define IN_CH 512
#define HEADS 4
#define OUT_CH 128
#define HC 512                 // HEADS*OUT_CH
#define NEG_SLOPE 0.2f

// fused-kernel block partitions
#define CVX_BLOCKS 5024        // N_PAD*IN_CH/8/256
#define CVW_BLOCKS 64          // (IN_CH/64)*(HC/64)
#define CNT_BLOCKS 1250        // N_EDGES/256

// gemm grid: 157 M-tiles x 4 N-tiles, m-major works, XCD-chunked
#define GEMM_WGS 628
#define GEMM_XQ 78             // 628/8
#define GEMM_XR 4              // 628%8

typedef __attribute__((ext_vector_type(8))) short short8;
typedef __attribute__((ext_vector_type(4))) float float4v;

// ---------------- edge-index dtype detection (inline, deterministic) ----------------
__device__ __forceinline__ int detect_is64(const int* __restrict__ ei32) {
    int is64 = 1;
    #pragma unroll
    for (int i = 0; i < 32; i++) is64 &= (ei32[2 * i + 1] == 0);
    return is64;
}

__device__ __forceinline__ int edge_at(const void* ei, int is64, long long idx) {
    return is64 ? (int)((const long long*)ei)[idx] : ((const int*)ei)[idx];
}

__device__ __forceinline__ unsigned short f2bf(float f) {
    union { float f; unsigned u; } v; v.f = f;
    unsigned r = v.u + 0x7fffu + ((v.u >> 16) & 1u);   // RNE
    return (unsigned short)(r >> 16);
}

// decode 8 packed bf16 (uint4) -> 8 floats
__device__ __forceinline__ void bf8_decode(uint4 r, float* f) {
    f[0] = __uint_as_float(r.x << 16); f[1] = __uint_as_float(r.x & 0xffff0000u);
    f[2] = __uint_as_float(r.y << 16); f[3] = __uint_as_float(r.y & 0xffff0000u);
    f[4] = __uint_as_float(r.z << 16); f[5] = __uint_as_float(r.z & 0xffff0000u);
    f[6] = __uint_as_float(r.w << 16); f[7] = __uint_as_float(r.w & 0xffff0000u);
}

__device__ __forceinline__ float leaky(float t) { return t > 0.f ? t : NEG_SLOPE * t; }

// pick w[hd] from a float4 of per-head weights (hd in 0..3) without scratch
__device__ __forceinline__ float sel_head(float4 w, int hd) {
    float lo = (hd & 1) ? w.y : w.x;
    float hi = (hd & 1) ? w.w : w.z;
    return (hd & 2) ? hi : lo;
}

// ---------------- K1: fused convert_x + convert_w(transpose) + count(+epos) ----------------
__global__ __launch_bounds__(256) void fusedA_kernel(const float* __restrict__ x,
                                                     const float* __restrict__ W,
                                                     unsigned short* __restrict__ xb,
                                                     unsigned short* __restrict__ Wt,
                                                     const void* __restrict__ ei,
                                                     int* __restrict__ counts,
                                                     int* __restrict__ epos) {
    __shared__ float tile[64][65];
    int b = blockIdx.x;
    if (b < CVX_BLOCKS) {
        size_t i = ((size_t)b * 256 + threadIdx.x) * 8;
        unsigned short o[8];
        if (i < (size_t)N_NODES * IN_CH) {
            float4 f0 = *(const float4*)&x[i];
            float4 f1 = *(const float4*)&x[i + 4];
            o[0] = f2bf(f0.x); o[1] = f2bf(f0.y); o[2] = f2bf(f0.z); o[3] = f2bf(f0.w);
            o[4] = f2bf(f1.x); o[5] = f2bf(f1.y); o[6] = f2bf(f1.z); o[7] = f2bf(f1.w);
        } else {
            for (int k = 0; k < 8; k++) o[k] = 0;
        }
        *(short8*)&xb[i] = *(short8*)o;
    } else if (b < CVX_BLOCKS + CVW_BLOCKS) {
        int idx = b - CVX_BLOCKS;
        int k0 = (idx & 7) * 64, n0 = (idx >> 3) * 64;
        int t = threadIdx.x, r = t >> 6, c = t & 63;
        for (int rr = r; rr < 64; rr += 4)
            tile[rr][c] = W[(size_t)(k0 + rr) * HC + n0 + c];
        __syncthreads();
        for (int rr = r; rr < 64; rr += 4)
            Wt[(size_t)(n0 + rr) * IN_CH + k0 + c] = f2bf(tile[c][rr]);
    } else {
        int is64 = detect_is64((const int*)ei);
        int e = (b - CVX_BLOCKS - CVW_BLOCKS) * 256 + threadIdx.x;
        if (e < N_EDGES) {
            int dst = edge_at(ei, is64, (long long)N_EDGES + e);
            int p = atomicAdd(&counts[dst], 1);
            epos[e] = p;                 // position within dst's segment (no 2nd atomic later)
        }
    }
}

// ---------------- bf16 MFMA GEMM (dbuf + counted vmcnt + swizzled LDS) + a_s/a_d epilogue ----
// xlb[M,HC](bf16) = A[M,K] @ Wt[N,K]^T.
// LDS k-slot swizzle: LDS[r][s] holds global k-slot s^((r>>1)&3); stage pre-swizzles the
// GLOBAL src (dest stays linear for global_load_lds, rule both-sides-or-neither);
// read at slot lk^((lm>>1)&3) -> 2-way banks (was 8-way).
// Double buffer: STAGE(next) issued before compute, s_waitcnt vmcnt(4) (counted, not 0),
// raw s_barrier + sched_barrier(0) fences.
__global__ __launch_bounds__(256) void gemm_kernel(const unsigned short* __restrict__ A,
                                                   const unsigned short* __restrict__ Bt,
                                                   unsigned short* __restrict__ Cb,
                                                   const float* __restrict__ att_s,
                                                   const float* __restrict__ att_d,
                                                   float* __restrict__ a_s,
                                                   float* __restrict__ a_d) {
    __shared__ __align__(16) unsigned short As[2][128 * 32];
    __shared__ __align__(16) unsigned short Bs[2][128 * 32];
    __shared__ float ssum[128][2];
    __shared__ float dsum[128][2];

    // bijective XCD-chunked swizzle (m204): all 4 N-tiles of an M-tile -> same XCD
    const int bid = blockIdx.x;
    const int xcd = bid & 7, rank = bid >> 3;
    const int w = (xcd < GEMM_XR) ? xcd * (GEMM_XQ + 1) + rank
                                  : GEMM_XR * (GEMM_XQ + 1) + (xcd - GEMM_XR) * GEMM_XQ + rank;
    const int bm = (w >> 2) * 128;
    const int bn = (w & 3) * 128;

    const int t = threadIdx.x;
    const int wv = t >> 6, lane = t & 63;
    const int wm = wv & 1, wn = wv >> 1;
    const int lm = lane & 15, lk = lane >> 4;

    float4v acc[4][4];
    #pragma unroll
    for (int i = 0; i < 4; i++)
        #pragma unroll
        for (int j = 0; j < 4; j++) acc[i][j] = (float4v){0.f, 0.f, 0.f, 0.f};

    const int srow = t >> 2;                                 // 0..63 (per q-half)
    const int sk   = ((t & 3) ^ ((t >> 3) & 3)) * 8;         // pre-swizzled global k-slot
    const int swr  = (lk ^ ((lm >> 1) & 3)) * 8;             // swizzled read slot

#define GEMM_STAGE(buf, kof)                                                                  \
    {                                                                                         \
        _Pragma("unroll")                                                                     \
        for (int q = 0; q < 2; q++) {                                                         \
            const unsigned short* gA = A + (size_t)(bm + q * 64 + srow) * IN_CH + (kof) + sk; \
            const unsigned short* gB = Bt + (size_t)(bn + q * 64 + srow) * IN_CH + (kof) + sk;\
            __builtin_amdgcn_global_load_lds((const __attribute__((address_space(1))) void*)gA,\
                (__attribute__((address_space(3))) void*)&As[buf][q * 2048 + t * 8], 16, 0, 0);\
            __builtin_amdgcn_global_load_lds((const __attribute__((address_space(1))) void*)gB,\
                (__attribute__((address_space(3))) void*)&Bs[buf][q * 2048 + t * 8], 16, 0, 0);\
        }                                                                                     \
    }

    GEMM_STAGE(0, 0);
    int cur = 0;
    for (int kk = 0; kk < 16; ++kk) {
        if (kk < 15) {
            GEMM_STAGE(cur ^ 1, (kk + 1) * 32);
            asm volatile("s_waitcnt vmcnt(4)" ::: "memory");   // this tile's 4 loads done
        } else {
            asm volatile("s_waitcnt vmcnt(0)" ::: "memory");
        }
        __builtin_amdgcn_s_barrier();
        __builtin_amdgcn_sched_barrier(0);                     // no ds_read hoist above barrier

        short8 af[4], bf[4];
        #pragma unroll
        for (int i = 0; i < 4; i++)
            af[i] = *(const short8*)&As[cur][(wm * 64 + i * 16 + lm) * 32 + swr];
        #pragma unroll
        for (int j = 0; j < 4; j++)
            bf[j] = *(const short8*)&Bs[cur][(wn * 64 + j * 16 + lm) * 32 + swr];
        #pragma unroll
        for (int i = 0; i < 4; i++)
            #pragma unroll
            for (int j = 0; j < 4; j++)
                acc[i][j] = __builtin_amdgcn_mfma_f32_16x16x32_bf16(af[i], bf[j], acc[i][j], 0, 0, 0);

        __builtin_amdgcn_sched_barrier(0);                     // reads stay inside the phase
        __builtin_amdgcn_s_barrier();
        cur ^= 1;
    }
#undef GEMM_STAGE

    // C store (flat [row][col] bf16)
    #pragma unroll
    for (int i = 0; i < 4; i++) {
        #pragma unroll
        for (int r = 0; r < 4; r++) {
            int row = bm + wm * 64 + i * 16 + lk * 4 + r;
            if (row < N_NODES) {
                #pragma unroll
                for (int j = 0; j < 4; j++) {
                    int col = bn + wn * 64 + j * 16 + lm;
                    Cb[(size_t)row * HC + col] = f2bf(acc[i][j][r]);
                }
            }
        }
    }

    // ---- attention-half epilogue: a_s/a_d for this block's 128 rows, head h ----
    const int h = bn >> 7;
    float as_w[4], ad_w[4];
    #pragma unroll
    for (int j = 0; j < 4; j++) {
        int col = bn + wn * 64 + j * 16 + lm;      // flat index into [4][128] att arrays
        as_w[j] = att_s[col];
        ad_w[j] = att_d[col];
    }
    float ps[4][4], pd[4][4];
    #pragma unroll
    for (int i = 0; i < 4; i++)
        #pragma unroll
        for (int r = 0; r < 4; r++) {
            float s = 0.f, d = 0.f;
            #pragma unroll
            for (int j = 0; j < 4; j++) { s += acc[i][j][r] * as_w[j]; d += acc[i][j][r] * ad_w[j]; }
            ps[i][r] = s; pd[i][r] = d;
        }
    #pragma unroll
    for (int off = 1; off < 16; off <<= 1) {
        #pragma unroll
        for (int i = 0; i < 4; i++)
            #pragma unroll
            for (int r = 0; r < 4; r++) {
                ps[i][r] += __shfl_xor(ps[i][r], off, 64);
                pd[i][r] += __shfl_xor(pd[i][r], off, 64);
            }
    }
    if (lm == 0) {
        #pragma unroll
        for (int i = 0; i < 4; i++)
            #pragma unroll
            for (int r = 0; r < 4; r++) {
                int rl = wm * 64 + i * 16 + lk * 4 + r;
                ssum[rl][wn] = ps[i][r];
                dsum[rl][wn] = pd[i][r];
            }
    }
    __syncthreads();
    if (t < 128) {
        int row = bm + t;
        if (row < N_NODES) {
            a_s[row * 4 + h] = ssum[t][0] + ssum[t][1];
            a_d[row * 4 + h] = dsum[t][0] + dsum[t][1];
        }
    }
}

// ---------------- K3: exclusive scan counts -> offsets (single block) ----------------
__global__ __launch_bounds__(1024) void scan_kernel(const int* __restrict__ counts,
                                                    int* __restrict__ offsets) {
    const int CHUNK = 20;                 // 1024*20 = 20480 >= N_NODES
    int tid = threadIdx.x;
    int base = tid * CHUNK;
    int c[CHUNK];
    #pragma unroll
    for (int k = 0; k < CHUNK; k++) {
        int i = base + k;
        c[k] = (i < N_NODES) ? counts[i] : 0;
    }
    int pre[CHUNK];
    int sum = 0;
    #pragma unroll
    for (int k = 0; k < CHUNK; k++) { pre[k] = sum; sum += c[k]; }

    int lane = tid & 63, wvv = tid >> 6;
    int s = sum;
    #pragma unroll
    for (int off = 1; off < 64; off <<= 1) {
        int u = __shfl_up(s, off, 64);
        if (lane >= off) s += u;
    }
    __shared__ int wsum[16];
    if (lane == 63) wsum[wvv] = s;
    __syncthreads();
    if (tid < 16) {
        int u = wsum[tid];
        #pragma unroll
        for (int off = 1; off < 16; off <<= 1) {
            int w = __shfl_up(u, off, 64);
            if (tid >= off) u += w;
        }
        wsum[tid] = u;
    }
    __syncthreads();
    int wbase = (wvv == 0) ? 0 : wsum[wvv - 1];
    int excl = wbase + s - sum;
    #pragma unroll
    for (int k = 0; k < CHUNK; k++) {
        int i = base + k;
        if (i < N_NODES) offsets[i] = excl + pre[k];
    }
    if (tid == 1023) offsets[N_NODES] = wbase + s;
}

// ---------------- K4: scatter + per-edge weights (no atomics — epos precomputed) ----------------
__global__ __launch_bounds__(256) void scatterw_kernel(const void* __restrict__ ei,
                                                       const int* __restrict__ offsets,
                                                       const int* __restrict__ epos,
                                                       int* __restrict__ sorted_src,
                                                       const float* __restrict__ a_s,
                                                       const float* __restrict__ a_d,
                                                       float* __restrict__ edge_w) {
    int is64 = detect_is64((const int*)ei);
    int e = blockIdx.x * 256 + threadIdx.x;
    if (e < N_EDGES) {
        int dst = edge_at(ei, is64, (long long)N_EDGES + e);
        int src = edge_at(ei, is64, e);
        int pos = offsets[dst] + epos[e];
        sorted_src[pos] = src;
        float4 as4 = *(const float4*)&a_s[src * 4];
        float4 ad4 = *(const float4*)&a_d[dst * 4];
        float4 w;
        w.x = __expf(leaky(as4.x + ad4.x));
        w.y = __expf(leaky(as4.y + ad4.y));
        w.z = __expf(leaky(as4.z + ad4.z));
        w.w = __expf(leaky(as4.w + ad4.w));
        *(float4*)&edge_w[(size_t)pos * 4] = w;
    }
}

// ---------------- segment softmax + weighted gather ----------------
// 4 waves per node (stride-16, 4-edge chunks each), partials combined via LDS.
// No max subtraction (logits bounded; fp32 exp safe; algebraically identical).
// Lane owns channels lane*8..+7 => head = lane>>4. Indices/weights wave-uniform.
__global__ __launch_bounds__(256) void gather_kernel(const unsigned short* __restrict__ xlb,
                                                     const float* __restrict__ a_s,
                                                     const float* __restrict__ a_d,
                                                     const int* __restrict__ offsets,
                                                     const int* __restrict__ sorted_src,
                                                     const float* __restrict__ edge_w,
                                                     const float* __restrict__ bias,
                                                     float* __restrict__ out) {
    __shared__ float cl[3][64][9];
    int sub = threadIdx.x >> 6;         // wave 0..3 of this node
    int node = blockIdx.x;              // grid = N_NODES
    int lane = threadIdx.x & 63;
    int hd = lane >> 4;
    int beg = offsets[node], end = offsets[node + 1];

    const unsigned short* xrow = xlb + lane * 8;
    float acc[8] = {0, 0, 0, 0, 0, 0, 0, 0};
    float denom = 0.f;

    if (sub == 0) {   // self-loop
        float4 as4 = *(const float4*)&a_s[node * 4];
        float4 ad4 = *(const float4*)&a_d[node * 4];
        float4 ws;
        ws.x = __expf(leaky(as4.x + ad4.x));
        ws.y = __expf(leaky(as4.y + ad4.y));
        ws.z = __expf(leaky(as4.z + ad4.z));
        ws.w = __expf(leaky(as4.w + ad4.w));
        float w = sel_head(ws, hd);
        denom = w;
        uint4 r = *(const uint4*)(xrow + (size_t)node * HC);
        float f[8];
        bf8_decode(r, f);
        #pragma unroll
        for (int k = 0; k < 8; k++) acc[k] = w * f[k];
    }

    for (int c0 = beg + sub * 4; c0 < end; c0 += 16) {
        int n = end - c0;
        if (n >= 4) {
            int s0 = sorted_src[c0];
            int s1 = sorted_src[c0 + 1];
            int s2 = sorted_src[c0 + 2];
            int s3 = sorted_src[c0 + 3];
            uint4 r0 = *(const uint4*)(xrow + (size_t)s0 * HC);
            uint4 r1 = *(const uint4*)(xrow + (size_t)s1 * HC);
            uint4 r2 = *(const uint4*)(xrow + (size_t)s2 * HC);
            uint4 r3 = *(const uint4*)(xrow + (size_t)s3 * HC);
            float4 wa = *(const float4*)&edge_w[(size_t)c0 * 4];
            float4 wb = *(const float4*)&edge_w[(size_t)(c0 + 1) * 4];
            float4 wc = *(const float4*)&edge_w[(size_t)(c0 + 2) * 4];
            float4 wd = *(const float4*)&edge_w[(size_t)(c0 + 3) * 4];
            float w0 = sel_head(wa, hd), w1 = sel_head(wb, hd);
            float w2 = sel_head(wc, hd), w3 = sel_head(wd, hd);
            denom += (w0 + w1) + (w2 + w3);
            float f0[8], f1[8], f2[8], f3[8];
            bf8_decode(r0, f0);
            bf8_decode(r1, f1);
            bf8_decode(r2, f2);
            bf8_decode(r3, f3);
            #pragma unroll
            for (int k = 0; k < 8; k++)
                acc[k] += (w0 * f0[k] + w1 * f1[k]) + (w2 * f2[k] + w3 * f3[k]);
        } else {
            for (int j = 0; j < n; j++) {
                int s0 = sorted_src[c0 + j];
                uint4 r0 = *(const uint4*)(xrow + (size_t)s0 * HC);
                float4 wa = *(const float4*)&edge_w[(size_t)(c0 + j) * 4];
                float w0 = sel_head(wa, hd);
                denom += w0;
                float f0[8];
                bf8_decode(r0, f0);
                #pragma unroll
                for (int k = 0; k < 8; k++) acc[k] += w0 * f0[k];
            }
        }
    }

    if (sub != 0) {
        #pragma unroll
        for (int k = 0; k < 8; k++) cl[sub - 1][lane][k] = acc[k];
        cl[sub - 1][lane][8] = denom;
    }
    __syncthreads();
    if (sub == 0) {
        #pragma unroll
        for (int p = 0; p < 3; p++) {
            #pragma unroll
            for (int k = 0; k < 8; k++) acc[k] += cl[p][lane][k];
            denom += cl[p][lane][8];
        }

        float rd = 0.25f / (denom + 1e-16f);   // fold head-mean into normalize
        float v[8];
        #pragma unroll
        for (int k = 0; k < 8; k++) {
            float t = acc[k] * rd;
            t += __shfl_xor(t, 16, 64);
            t += __shfl_xor(t, 32, 64);
            v[k] = t;
        }
        if (hd == 0) {
            float4 b0 = *(const float4*)&bias[lane * 8];
            float4 b1 = *(const float4*)&bias[lane * 8 + 4];
            float o[8];
            o[0] = v[0] + b0.x; o[1] = v[1] + b0.y; o[2] = v[2] + b0.z; o[3] = v[3] + b0.w;
            o[4] = v[4] + b1.x; o[5] = v[5] + b1.y; o[6] = v[6] + b1.z; o[7] = v[7] + b1.w;
            #pragma unroll
            for (int k = 0; k < 8; k++) o[k] = o[k] > 0.f ? o[k] : expm1f(o[k]);
            *(float4*)&out[(size_t)node * OUT_CH + lane * 8]     = make_float4(o[0], o[1], o[2], o[3]);
            *(float4*)&out[(size_t)node * OUT_CH + lane * 8 + 4] = make_float4(o[4], o[5], o[6], o[7]);
        }
    }
}

// ---------------- launch ----------------
extern "C" void kernel_launch(void* const* d_in, const int* in_sizes, int n_in,
                              void* d_out, int out_size, void* d_ws, size_t ws_size,
                              hipStream_t stream) {
    const float* x       = (const float*)d_in[0];
    const float* W       = (const float*)d_in[1];
    const float* att_src = (const float*)d_in[2];
    const float* att_dst = (const float*)d_in[3];
    const float* bias    = (const float*)d_in[4];
    const void*  ei      = d_in[5];
    float* out = (float*)d_out;

    char* ws = (char*)d_ws;
    size_t off = 0;
    unsigned short* xlb = (unsigned short*)(ws + off); off += (size_t)N_PAD * HC * sizeof(unsigned short);
    float* a_s     = (float*)(ws + off); off += (size_t)N_NODES * HEADS * sizeof(float);
    float* a_d     = (float*)(ws + off); off += (size_t)N_NODES * HEADS * sizeof(float);
    int* counts    = (int*)(ws + off);   off += (size_t)N_NODES * sizeof(int);
    int* offsets   = (int*)(ws + off);   off += (size_t)(N_NODES + 1) * sizeof(int);
    off = (off + 15) & ~(size_t)15;
    int* epos      = (int*)(ws + off);   off += (size_t)N_EDGES * sizeof(int);
    int* sorted_src = (int*)(ws + off);  off += (size_t)N_EDGES * sizeof(int);
    off = (off + 15) & ~(size_t)15;
    float* edge_w  = (float*)(ws + off); off += (size_t)N_EDGES * HEADS * sizeof(float);
    unsigned short* xb = (unsigned short*)(ws + off); off += (size_t)N_PAD * IN_CH * sizeof(unsigned short);
    unsigned short* Wt = (unsigned short*)(ws + off); off += (size_t)IN_CH * HC * sizeof(unsigned short);

    hipMemsetAsync(counts, 0, N_NODES * sizeof(int), stream);
    fusedA_kernel<<<CVX_BLOCKS + CVW_BLOCKS + CNT_BLOCKS, 256, 0, stream>>>(x, W, xb, Wt, ei, counts, epos);
    gemm_kernel<<<GEMM_WGS, 256, 0, stream>>>(xb, Wt, xlb, att_src, att_dst, a_s, a_d);
    scan_kernel<<<1, 1024, 0, stream>>>(counts, offsets);
    scatterw_kernel<<<(N_EDGES + 255) / 256, 256, 0, stream>>>(ei, offsets, epos, sorted_src, a_s, a_d, edge_w);
    gather_kernel<<<N_NODES, 256, 0, stream>>>(xlb, a_s, a_d, offsets, sorted_src, edge_w, bias, out);
}

// Round 6
// 209.719 us; speedup vs baseline: 1.3009x; 1.0218x over previous
//
#include <hip/hip_runtime.h>
#include <math.h>

#define N_NODES 20000
#define N_PAD 20096            // N_NODES rounded up to 128 (GEMM M-tile)
#define N_EDGES 320000
#define IN_CH 512
#define HEADS 4
#define OUT_CH 128
#define HC 512                 // HEADS*OUT_CH
#define NEG_SLOPE 0.2f

// fused-kernel block partitions
#define CVX_BLOCKS 5024        // N_PAD*IN_CH/8/256
#define CVW_BLOCKS 64          // (IN_CH/64)*(HC/64)
#define CNT_BLOCKS 1250        // N_EDGES/256

// gemm grid: 314 M-tiles (64 rows) x 4 N-tiles (128 cols), m-major, XCD-chunked
#define GEMM_WGS 1256          // 1256 % 8 == 0 -> exact bijective chunking, 157/XCD

typedef __attribute__((ext_vector_type(8))) short short8;
typedef __attribute__((ext_vector_type(4))) float float4v;

// ---------------- edge-index dtype detection (inline, deterministic) ----------------
__device__ __forceinline__ int detect_is64(const int* __restrict__ ei32) {
    int is64 = 1;
    #pragma unroll
    for (int i = 0; i < 32; i++) is64 &= (ei32[2 * i + 1] == 0);
    return is64;
}

__device__ __forceinline__ int edge_at(const void* ei, int is64, long long idx) {
    return is64 ? (int)((const long long*)ei)[idx] : ((const int*)ei)[idx];
}

__device__ __forceinline__ unsigned short f2bf(float f) {
    union { float f; unsigned u; } v; v.f = f;
    unsigned r = v.u + 0x7fffu + ((v.u >> 16) & 1u);   // RNE
    return (unsigned short)(r >> 16);
}

// decode 8 packed bf16 (uint4) -> 8 floats
__device__ __forceinline__ void bf8_decode(uint4 r, float* f) {
    f[0] = __uint_as_float(r.x << 16); f[1] = __uint_as_float(r.x & 0xffff0000u);
    f[2] = __uint_as_float(r.y << 16); f[3] = __uint_as_float(r.y & 0xffff0000u);
    f[4] = __uint_as_float(r.z << 16); f[5] = __uint_as_float(r.z & 0xffff0000u);
    f[6] = __uint_as_float(r.w << 16); f[7] = __uint_as_float(r.w & 0xffff0000u);
}

__device__ __forceinline__ float leaky(float t) { return t > 0.f ? t : NEG_SLOPE * t; }

// pick w[hd] from a float4 of per-head weights (hd in 0..3) without scratch
__device__ __forceinline__ float sel_head(float4 w, int hd) {
    float lo = (hd & 1) ? w.y : w.x;
    float hi = (hd & 1) ? w.w : w.z;
    return (hd & 2) ? hi : lo;
}

// ---------------- K1: fused convert_x + convert_w(transpose) + count(+epos) ----------------
__global__ __launch_bounds__(256) void fusedA_kernel(const float* __restrict__ x,
                                                     const float* __restrict__ W,
                                                     unsigned short* __restrict__ xb,
                                                     unsigned short* __restrict__ Wt,
                                                     const void* __restrict__ ei,
                                                     int* __restrict__ counts,
                                                     int* __restrict__ epos) {
    __shared__ float tile[64][65];
    int b = blockIdx.x;
    if (b < CVX_BLOCKS) {
        size_t i = ((size_t)b * 256 + threadIdx.x) * 8;
        unsigned short o[8];
        if (i < (size_t)N_NODES * IN_CH) {
            float4 f0 = *(const float4*)&x[i];
            float4 f1 = *(const float4*)&x[i + 4];
            o[0] = f2bf(f0.x); o[1] = f2bf(f0.y); o[2] = f2bf(f0.z); o[3] = f2bf(f0.w);
            o[4] = f2bf(f1.x); o[5] = f2bf(f1.y); o[6] = f2bf(f1.z); o[7] = f2bf(f1.w);
        } else {
            for (int k = 0; k < 8; k++) o[k] = 0;
        }
        *(short8*)&xb[i] = *(short8*)o;
    } else if (b < CVX_BLOCKS + CVW_BLOCKS) {
        int idx = b - CVX_BLOCKS;
        int k0 = (idx & 7) * 64, n0 = (idx >> 3) * 64;
        int t = threadIdx.x, r = t >> 6, c = t & 63;
        for (int rr = r; rr < 64; rr += 4)
            tile[rr][c] = W[(size_t)(k0 + rr) * HC + n0 + c];
        __syncthreads();
        for (int rr = r; rr < 64; rr += 4)
            Wt[(size_t)(n0 + rr) * IN_CH + k0 + c] = f2bf(tile[c][rr]);
    } else {
        int is64 = detect_is64((const int*)ei);
        int e = (b - CVX_BLOCKS - CVW_BLOCKS) * 256 + threadIdx.x;
        if (e < N_EDGES) {
            int dst = edge_at(ei, is64, (long long)N_EDGES + e);
            int p = atomicAdd(&counts[dst], 1);
            epos[e] = p;                 // position within dst's segment (no 2nd atomic later)
        }
    }
}

// ---------------- bf16 MFMA GEMM (64x128 tile, 3-buf depth-2 prefetch) + a_s/a_d epilogue ----
// 1256 blocks (4.9/CU) for TLP; counted vmcnt(6/3/0); k-slot XOR swizzle applied on the
// GLOBAL source (LDS dest linear, both-sides-or-neither) and undone at read time.
__global__ __launch_bounds__(256) void gemm_kernel(const unsigned short* __restrict__ A,
                                                   const unsigned short* __restrict__ Bt,
                                                   unsigned short* __restrict__ Cb,
                                                   const float* __restrict__ att_s,
                                                   const float* __restrict__ att_d,
                                                   float* __restrict__ a_s,
                                                   float* __restrict__ a_d) {
    __shared__ __align__(16) unsigned short As[3][64 * 32];
    __shared__ __align__(16) unsigned short Bs[3][128 * 32];
    __shared__ float ssum[64][2];
    __shared__ float dsum[64][2];

    // bijective XCD chunking: 157 consecutive m-major tiles per XCD
    const int bid = blockIdx.x;
    const int w = (bid & 7) * 157 + (bid >> 3);
    const int bm = (w >> 2) * 64;
    const int bn = (w & 3) * 128;

    const int t = threadIdx.x;
    const int wv = t >> 6, lane = t & 63;
    const int wm = wv & 1, wn = wv >> 1;
    const int lm = lane & 15, lk = lane >> 4;

    float4v acc[2][4];
    #pragma unroll
    for (int i = 0; i < 2; i++)
        #pragma unroll
        for (int j = 0; j < 4; j++) acc[i][j] = (float4v){0.f, 0.f, 0.f, 0.f};

    const int srow = t >> 2;                                 // A row 0..63 / B half-row
    const int sk   = ((t & 3) ^ ((t >> 3) & 3)) * 8;         // pre-swizzled global k-slot
    const int swr  = (lk ^ ((lm >> 1) & 3)) * 8;             // swizzled read slot

#define GEMM_STAGE(buf, kof)                                                                   \
    {                                                                                          \
        const unsigned short* gA = A + (size_t)(bm + srow) * IN_CH + (kof) + sk;               \
        __builtin_amdgcn_global_load_lds((const __attribute__((address_space(1))) void*)gA,    \
            (__attribute__((address_space(3))) void*)&As[buf][t * 8], 16, 0, 0);               \
        _Pragma("unroll")                                                                      \
        for (int q = 0; q < 2; q++) {                                                          \
            const unsigned short* gB = Bt + (size_t)(bn + q * 64 + srow) * IN_CH + (kof) + sk; \
            __builtin_amdgcn_global_load_lds((const __attribute__((address_space(1))) void*)gB,\
                (__attribute__((address_space(3))) void*)&Bs[buf][q * 2048 + t * 8], 16, 0, 0);\
        }                                                                                      \
    }

    GEMM_STAGE(0, 0);
    GEMM_STAGE(1, 32);
    #pragma unroll
    for (int kk = 0; kk < 16; ++kk) {
        const int cur = kk % 3;
        if (kk < 14) {
            GEMM_STAGE((kk + 2) % 3, (kk + 2) * 32);
            asm volatile("s_waitcnt vmcnt(6)" ::: "memory");   // stage kk's 3 loads done
        } else if (kk == 14) {
            asm volatile("s_waitcnt vmcnt(3)" ::: "memory");
        } else {
            asm volatile("s_waitcnt vmcnt(0)" ::: "memory");
        }
        __builtin_amdgcn_s_barrier();
        __builtin_amdgcn_sched_barrier(0);                     // no ds_read hoist above barrier

        short8 af[2], bf[4];
        #pragma unroll
        for (int i = 0; i < 2; i++)
            af[i] = *(const short8*)&As[cur][(wm * 32 + i * 16 + lm) * 32 + swr];
        #pragma unroll
        for (int j = 0; j < 4; j++)
            bf[j] = *(const short8*)&Bs[cur][(wn * 64 + j * 16 + lm) * 32 + swr];
        #pragma unroll
        for (int i = 0; i < 2; i++)
            #pragma unroll
            for (int j = 0; j < 4; j++)
                acc[i][j] = __builtin_amdgcn_mfma_f32_16x16x32_bf16(af[i], bf[j], acc[i][j], 0, 0, 0);

        __builtin_amdgcn_sched_barrier(0);                     // reads stay inside the phase
        __builtin_amdgcn_s_barrier();
    }
#undef GEMM_STAGE

    // C store (flat [row][col] bf16)
    #pragma unroll
    for (int i = 0; i < 2; i++) {
        #pragma unroll
        for (int r = 0; r < 4; r++) {
            int row = bm + wm * 32 + i * 16 + lk * 4 + r;
            if (row < N_NODES) {
                #pragma unroll
                for (int j = 0; j < 4; j++) {
                    int col = bn + wn * 64 + j * 16 + lm;
                    Cb[(size_t)row * HC + col] = f2bf(acc[i][j][r]);
                }
            }
        }
    }

    // ---- attention-half epilogue: a_s/a_d for this block's 64 rows, head h = bn>>7 ----
    const int h = bn >> 7;
    float as_w[4], ad_w[4];
    #pragma unroll
    for (int j = 0; j < 4; j++) {
        int col = bn + wn * 64 + j * 16 + lm;      // flat index into [4][128] att arrays
        as_w[j] = att_s[col];
        ad_w[j] = att_d[col];
    }
    float ps[2][4], pd[2][4];
    #pragma unroll
    for (int i = 0; i < 2; i++)
        #pragma unroll
        for (int r = 0; r < 4; r++) {
            float s = 0.f, d = 0.f;
            #pragma unroll
            for (int j = 0; j < 4; j++) { s += acc[i][j][r] * as_w[j]; d += acc[i][j][r] * ad_w[j]; }
            ps[i][r] = s; pd[i][r] = d;
        }
    #pragma unroll
    for (int off = 1; off < 16; off <<= 1) {
        #pragma unroll
        for (int i = 0; i < 2; i++)
            #pragma unroll
            for (int r = 0; r < 4; r++) {
                ps[i][r] += __shfl_xor(ps[i][r], off, 64);
                pd[i][r] += __shfl_xor(pd[i][r], off, 64);
            }
    }
    if (lm == 0) {
        #pragma unroll
        for (int i = 0; i < 2; i++)
            #pragma unroll
            for (int r = 0; r < 4; r++) {
                int rl = wm * 32 + i * 16 + lk * 4 + r;
                ssum[rl][wn] = ps[i][r];
                dsum[rl][wn] = pd[i][r];
            }
    }
    __syncthreads();
    if (t < 64) {
        int row = bm + t;
        if (row < N_NODES) {
            a_s[row * 4 + h] = ssum[t][0] + ssum[t][1];
            a_d[row * 4 + h] = dsum[t][0] + dsum[t][1];
        }
    }
}

// ---------------- K3: exclusive scan counts -> offsets (single block) ----------------
__global__ __launch_bounds__(1024) void scan_kernel(const int* __restrict__ counts,
                                                    int* __restrict__ offsets) {
    const int CHUNK = 20;                 // 1024*20 = 20480 >= N_NODES
    int tid = threadIdx.x;
    int base = tid * CHUNK;
    int c[CHUNK];
    #pragma unroll
    for (int k = 0; k < CHUNK; k++) {
        int i = base + k;
        c[k] = (i < N_NODES) ? counts[i] : 0;
    }
    int pre[CHUNK];
    int sum = 0;
    #pragma unroll
    for (int k = 0; k < CHUNK; k++) { pre[k] = sum; sum += c[k]; }

    int lane = tid & 63, wvv = tid >> 6;
    int s = sum;
    #pragma unroll
    for (int off = 1; off < 64; off <<= 1) {
        int u = __shfl_up(s, off, 64);
        if (lane >= off) s += u;
    }
    __shared__ int wsum[16];
    if (lane == 63) wsum[wvv] = s;
    __syncthreads();
    if (tid < 16) {
        int u = wsum[tid];
        #pragma unroll
        for (int off = 1; off < 16; off <<= 1) {
            int w = __shfl_up(u, off, 64);
            if (tid >= off) u += w;
        }
        wsum[tid] = u;
    }
    __syncthreads();
    int wbase = (wvv == 0) ? 0 : wsum[wvv - 1];
    int excl = wbase + s - sum;
    #pragma unroll
    for (int k = 0; k < CHUNK; k++) {
        int i = base + k;
        if (i < N_NODES) offsets[i] = excl + pre[k];
    }
    if (tid == 1023) offsets[N_NODES] = wbase + s;
}

// ---------------- K4: scatter + per-edge weights (no atomics — epos precomputed) ----------------
__global__ __launch_bounds__(256) void scatterw_kernel(const void* __restrict__ ei,
                                                       const int* __restrict__ offsets,
                                                       const int* __restrict__ epos,
                                                       int* __restrict__ sorted_src,
                                                       const float* __restrict__ a_s,
                                                       const float* __restrict__ a_d,
                                                       float* __restrict__ edge_w) {
    int is64 = detect_is64((const int*)ei);
    int e = blockIdx.x * 256 + threadIdx.x;
    if (e < N_EDGES) {
        int dst = edge_at(ei, is64, (long long)N_EDGES + e);
        int src = edge_at(ei, is64, e);
        int pos = offsets[dst] + epos[e];
        sorted_src[pos] = src;
        float4 as4 = *(const float4*)&a_s[src * 4];
        float4 ad4 = *(const float4*)&a_d[dst * 4];
        float4 w;
        w.x = __expf(leaky(as4.x + ad4.x));
        w.y = __expf(leaky(as4.y + ad4.y));
        w.z = __expf(leaky(as4.z + ad4.z));
        w.w = __expf(leaky(as4.w + ad4.w));
        *(float4*)&edge_w[(size_t)pos * 4] = w;
    }
}

// ---------------- segment softmax + weighted gather (2 waves/node, pipelined) ----------------
// Index/weight loads for chunk i+1 are prefetched before chunk i's row loads are consumed,
// breaking the 2-level dependent-load chain. Tail handled by clamped index + zero weight
// (no divergent tail loop). No max subtraction (logits bounded; algebraically identical).
__global__ __launch_bounds__(256) void gather_kernel(const unsigned short* __restrict__ xlb,
                                                     const float* __restrict__ a_s,
                                                     const float* __restrict__ a_d,
                                                     const int* __restrict__ offsets,
                                                     const int* __restrict__ sorted_src,
                                                     const float* __restrict__ edge_w,
                                                     const float* __restrict__ bias,
                                                     float* __restrict__ out) {
    __shared__ float cl[2][64][9];
    int wv = threadIdx.x >> 6;
    int nib = wv >> 1;                  // node in block (0..1)
    int sub = wv & 1;                   // which half-wave of the node
    int node = blockIdx.x * 2 + nib;    // grid = N_NODES/2
    int lane = threadIdx.x & 63;
    int hd = lane >> 4;
    int beg = offsets[node], end = offsets[node + 1];

    const unsigned short* xrow = xlb + lane * 8;
    float acc[8] = {0, 0, 0, 0, 0, 0, 0, 0};
    float denom = 0.f;

    // preload first chunk's indices+weights (clamped index, OOB slots zero-weighted)
    int c0 = beg + sub * 4;
    int s0 = 0, s1 = 0, s2 = 0, s3 = 0;
    float w0 = 0.f, w1 = 0.f, w2 = 0.f, w3 = 0.f;
    if (c0 < end) {
        int lim = end - 1;
        int i1 = c0 + 1 > lim ? lim : c0 + 1;
        int i2 = c0 + 2 > lim ? lim : c0 + 2;
        int i3 = c0 + 3 > lim ? lim : c0 + 3;
        s0 = sorted_src[c0]; s1 = sorted_src[i1]; s2 = sorted_src[i2]; s3 = sorted_src[i3];
        float4 t0 = *(const float4*)&edge_w[(size_t)c0 * 4];
        float4 t1 = *(const float4*)&edge_w[(size_t)i1 * 4];
        float4 t2 = *(const float4*)&edge_w[(size_t)i2 * 4];
        float4 t3 = *(const float4*)&edge_w[(size_t)i3 * 4];
        w0 = sel_head(t0, hd);
        w1 = (c0 + 1 < end) ? sel_head(t1, hd) : 0.f;
        w2 = (c0 + 2 < end) ? sel_head(t2, hd) : 0.f;
        w3 = (c0 + 3 < end) ? sel_head(t3, hd) : 0.f;
    }

    if (sub == 0) {   // self-loop
        float4 as4 = *(const float4*)&a_s[node * 4];
        float4 ad4 = *(const float4*)&a_d[node * 4];
        float4 ws;
        ws.x = __expf(leaky(as4.x + ad4.x));
        ws.y = __expf(leaky(as4.y + ad4.y));
        ws.z = __expf(leaky(as4.z + ad4.z));
        ws.w = __expf(leaky(as4.w + ad4.w));
        float w = sel_head(ws, hd);
        denom = w;
        uint4 r = *(const uint4*)(xrow + (size_t)node * HC);
        float f[8];
        bf8_decode(r, f);
        #pragma unroll
        for (int k = 0; k < 8; k++) acc[k] = w * f[k];
    }

    for (; c0 < end; c0 += 8) {
        // issue row loads for current chunk
        uint4 r0 = *(const uint4*)(xrow + (size_t)s0 * HC);
        uint4 r1 = *(const uint4*)(xrow + (size_t)s1 * HC);
        uint4 r2 = *(const uint4*)(xrow + (size_t)s2 * HC);
        uint4 r3 = *(const uint4*)(xrow + (size_t)s3 * HC);

        // prefetch next chunk's indices+weights (overlaps row-load latency)
        int c1 = c0 + 8;
        int n0 = 0, n1 = 0, n2 = 0, n3 = 0;
        float v0 = 0.f, v1 = 0.f, v2 = 0.f, v3 = 0.f;
        if (c1 < end) {
            int lim = end - 1;
            int i1 = c1 + 1 > lim ? lim : c1 + 1;
            int i2 = c1 + 2 > lim ? lim : c1 + 2;
            int i3 = c1 + 3 > lim ? lim : c1 + 3;
            n0 = sorted_src[c1]; n1 = sorted_src[i1]; n2 = sorted_src[i2]; n3 = sorted_src[i3];
            float4 t0 = *(const float4*)&edge_w[(size_t)c1 * 4];
            float4 t1 = *(const float4*)&edge_w[(size_t)i1 * 4];
            float4 t2 = *(const float4*)&edge_w[(size_t)i2 * 4];
            float4 t3 = *(const float4*)&edge_w[(size_t)i3 * 4];
            v0 = sel_head(t0, hd);
            v1 = (c1 + 1 < end) ? sel_head(t1, hd) : 0.f;
            v2 = (c1 + 2 < end) ? sel_head(t2, hd) : 0.f;
            v3 = (c1 + 3 < end) ? sel_head(t3, hd) : 0.f;
        }

        denom += (w0 + w1) + (w2 + w3);
        float f0[8], f1[8], f2[8], f3[8];
        bf8_decode(r0, f0);
        bf8_decode(r1, f1);
        bf8_decode(r2, f2);
        bf8_decode(r3, f3);
        #pragma unroll
        for (int k = 0; k < 8; k++)
            acc[k] += (w0 * f0[k] + w1 * f1[k]) + (w2 * f2[k] + w3 * f3[k]);

        s0 = n0; s1 = n1; s2 = n2; s3 = n3;
        w0 = v0; w1 = v1; w2 = v2; w3 = v3;
    }

    if (sub == 1) {
        #pragma unroll
        for (int k = 0; k < 8; k++) cl[nib][lane][k] = acc[k];
        cl[nib][lane][8] = denom;
    }
    __syncthreads();
    if (sub == 0) {
        #pragma unroll
        for (int k = 0; k < 8; k++) acc[k] += cl[nib][lane][k];
        denom += cl[nib][lane][8];

        float rd = 0.25f / (denom + 1e-16f);   // fold head-mean into normalize
        float v[8];
        #pragma unroll
        for (int k = 0; k < 8; k++) {
            float t = acc[k] * rd;
            t += __shfl_xor(t, 16, 64);
            t += __shfl_xor(t, 32, 64);
            v[k] = t;
        }
        if (hd == 0) {
            float4 b0 = *(const float4*)&bias[lane * 8];
            float4 b1 = *(const float4*)&bias[lane * 8 + 4];
            float o[8];
            o[0] = v[0] + b0.x; o[1] = v[1] + b0.y; o[2] = v[2] + b0.z; o[3] = v[3] + b0.w;
            o[4] = v[4] + b1.x; o[5] = v[5] + b1.y; o[6] = v[6] + b1.z; o[7] = v[7] + b1.w;
            #pragma unroll
            for (int k = 0; k < 8; k++) o[k] = o[k] > 0.f ? o[k] : expm1f(o[k]);
            *(float4*)&out[(size_t)node * OUT_CH + lane * 8]     = make_float4(o[0], o[1], o[2], o[3]);
            *(float4*)&out[(size_t)node * OUT_CH + lane * 8 + 4] = make_float4(o[4], o[5], o[6], o[7]);
        }
    }
}

// ---------------- launch ----------------
extern "C" void kernel_launch(void* const* d_in, const int* in_sizes, int n_in,
                              void* d_out, int out_size, void* d_ws, size_t ws_size,
                              hipStream_t stream) {
    const float* x       = (const float*)d_in[0];
    const float* W       = (const float*)d_in[1];
    const float* att_src = (const float*)d_in[2];
    const float* att_dst = (const float*)d_in[3];
    const float* bias    = (const float*)d_in[4];
    const void*  ei      = d_in[5];
    float* out = (float*)d_out;

    char* ws = (char*)d_ws;
    size_t off = 0;
    unsigned short* xlb = (unsigned short*)(ws + off); off += (size_t)N_PAD * HC * sizeof(unsigned short);
    float* a_s     = (float*)(ws + off); off += (size_t)N_NODES * HEADS * sizeof(float);
    float* a_d     = (float*)(ws + off); off += (size_t)N_NODES * HEADS * sizeof(float);
    int* counts    = (int*)(ws + off);   off += (size_t)N_NODES * sizeof(int);
    int* offsets   = (int*)(ws + off);   off += (size_t)(N_NODES + 1) * sizeof(int);
    off = (off + 15) & ~(size_t)15;
    int* epos      = (int*)(ws + off);   off += (size_t)N_EDGES * sizeof(int);
    int* sorted_src = (int*)(ws + off);  off += (size_t)N_EDGES * sizeof(int);
    off = (off + 15) & ~(size_t)15;
    float* edge_w  = (float*)(ws + off); off += (size_t)N_EDGES * HEADS * sizeof(float);
    unsigned short* xb = (unsigned short*)(ws + off); off += (size_t)N_PAD * IN_CH * sizeof(unsigned short);
    unsigned short* Wt = (unsigned short*)(ws + off); off += (size_t)IN_CH * HC * sizeof(unsigned short);

    hipMemsetAsync(counts, 0, N_NODES * sizeof(int), stream);
    fusedA_kernel<<<CVX_BLOCKS + CVW_BLOCKS + CNT_BLOCKS, 256, 0, stream>>>(x, W, xb, Wt, ei, counts, epos);
    gemm_kernel<<<GEMM_WGS, 256, 0, stream>>>(xb, Wt, xlb, att_src, att_dst, a_s, a_d);
    scan_kernel<<<1, 1024, 0, stream>>>(counts, offsets);
    scatterw_kernel<<<(N_EDGES + 255) / 256, 256, 0, stream>>>(ei, offsets, epos, sorted_src, a_s, a_d, edge_w);
    gather_kernel<<<N_NODES / 2, 256, 0, stream>>>(xlb, a_s, a_d, offsets, sorted_src, edge_w, bias, out);
}

// Round 7
// 208.557 us; speedup vs baseline: 1.3081x; 1.0056x over previous
//
#include <hip/hip_runtime.h>
#include <math.h>

#define N_NODES 20000
#define N_PAD 20096            // N_NODES rounded up to 128 (GEMM M-tile)
#define N_EDGES 320000
#define IN_CH 512
#define HEADS 4
#define OUT_CH 128
#define HC 512                 // HEADS*OUT_CH
#define NEG_SLOPE 0.2f

// fused-kernel block partitions
#define CVX_BLOCKS 5024        // N_PAD*IN_CH/8/256
#define CVW_BLOCKS 64          // (IN_CH/64)*(HC/64)
#define CNT_BLOCKS 1250        // N_EDGES/256

// gemm grid: 314 M-tiles (64 rows) x 2 N-halves (256 cols), m-major, XCD-chunked
#define GEMM_WGS 628
#define GEMM_XQ 78             // 628/8
#define GEMM_XR 4              // 628%8

typedef __attribute__((ext_vector_type(8))) short short8;
typedef __attribute__((ext_vector_type(4))) float float4v;

// ---------------- edge-index dtype detection (inline, deterministic) ----------------
__device__ __forceinline__ int detect_is64(const int* __restrict__ ei32) {
    int is64 = 1;
    #pragma unroll
    for (int i = 0; i < 32; i++) is64 &= (ei32[2 * i + 1] == 0);
    return is64;
}

__device__ __forceinline__ int edge_at(const void* ei, int is64, long long idx) {
    return is64 ? (int)((const long long*)ei)[idx] : ((const int*)ei)[idx];
}

__device__ __forceinline__ unsigned short f2bf(float f) {
    union { float f; unsigned u; } v; v.f = f;
    unsigned r = v.u + 0x7fffu + ((v.u >> 16) & 1u);   // RNE
    return (unsigned short)(r >> 16);
}

// decode 8 packed bf16 (uint4) -> 8 floats
__device__ __forceinline__ void bf8_decode(uint4 r, float* f) {
    f[0] = __uint_as_float(r.x << 16); f[1] = __uint_as_float(r.x & 0xffff0000u);
    f[2] = __uint_as_float(r.y << 16); f[3] = __uint_as_float(r.y & 0xffff0000u);
    f[4] = __uint_as_float(r.z << 16); f[5] = __uint_as_float(r.z & 0xffff0000u);
    f[6] = __uint_as_float(r.w << 16); f[7] = __uint_as_float(r.w & 0xffff0000u);
}

__device__ __forceinline__ float leaky(float t) { return t > 0.f ? t : NEG_SLOPE * t; }

// pick w[hd] from a float4 of per-head weights (hd in 0..3) without scratch
__device__ __forceinline__ float sel_head(float4 w, int hd) {
    float lo = (hd & 1) ? w.y : w.x;
    float hi = (hd & 1) ? w.w : w.z;
    return (hd & 2) ? hi : lo;
}

// ---------------- K1: fused convert_x + convert_w(transpose) + count(+epos) ----------------
__global__ __launch_bounds__(256) void fusedA_kernel(const float* __restrict__ x,
                                                     const float* __restrict__ W,
                                                     unsigned short* __restrict__ xb,
                                                     unsigned short* __restrict__ Wt,
                                                     const void* __restrict__ ei,
                                                     int* __restrict__ counts,
                                                     int* __restrict__ epos) {
    __shared__ float tile[64][65];
    int b = blockIdx.x;
    if (b < CVX_BLOCKS) {
        size_t i = ((size_t)b * 256 + threadIdx.x) * 8;
        unsigned short o[8];
        if (i < (size_t)N_NODES * IN_CH) {
            float4 f0 = *(const float4*)&x[i];
            float4 f1 = *(const float4*)&x[i + 4];
            o[0] = f2bf(f0.x); o[1] = f2bf(f0.y); o[2] = f2bf(f0.z); o[3] = f2bf(f0.w);
            o[4] = f2bf(f1.x); o[5] = f2bf(f1.y); o[6] = f2bf(f1.z); o[7] = f2bf(f1.w);
        } else {
            for (int k = 0; k < 8; k++) o[k] = 0;
        }
        *(short8*)&xb[i] = *(short8*)o;
    } else if (b < CVX_BLOCKS + CVW_BLOCKS) {
        int idx = b - CVX_BLOCKS;
        int k0 = (idx & 7) * 64, n0 = (idx >> 3) * 64;
        int t = threadIdx.x, r = t >> 6, c = t & 63;
        for (int rr = r; rr < 64; rr += 4)
            tile[rr][c] = W[(size_t)(k0 + rr) * HC + n0 + c];
        __syncthreads();
        for (int rr = r; rr < 64; rr += 4)
            Wt[(size_t)(n0 + rr) * IN_CH + k0 + c] = f2bf(tile[c][rr]);
    } else {
        int is64 = detect_is64((const int*)ei);
        int e = (b - CVX_BLOCKS - CVW_BLOCKS) * 256 + threadIdx.x;
        if (e < N_EDGES) {
            int dst = edge_at(ei, is64, (long long)N_EDGES + e);
            int p = atomicAdd(&counts[dst], 1);
            epos[e] = p;                 // position within dst's segment (no 2nd atomic later)
        }
    }
}

// ---------------- bf16 MFMA GEMM (64x256 tile, full-head waves) + a_s/a_d epilogue ----------
// Tile 64(M) x 256(N = 2 heads). Wave wv: wm=wv&1 -> M-half (32 rows), wn=wv>>1 -> head
// (128 cols). 16 MFMA/wave/step vs 5 staged loads/thread/step; A re-read 2x (was 4x).
// 2-buffer depth-1 prefetch, counted vmcnt(5); k-slot XOR swizzle on GLOBAL source
// (LDS dest linear), undone at read. 3 blocks/CU via __launch_bounds__(256,3).
// Each wave owns a full head -> a_s/a_d epilogue is pure in-wave shuffle reduce.
__global__ __launch_bounds__(256, 3) void gemm_kernel(const unsigned short* __restrict__ A,
                                                      const unsigned short* __restrict__ Bt,
                                                      unsigned short* __restrict__ Cb,
                                                      const float* __restrict__ att_s,
                                                      const float* __restrict__ att_d,
                                                      float* __restrict__ a_s,
                                                      float* __restrict__ a_d) {
    __shared__ __align__(16) unsigned short As[2][64 * 32];
    __shared__ __align__(16) unsigned short Bs[2][256 * 32];

    // bijective XCD-chunked swizzle (m204): consecutive w on one XCD; m-major pairs
    // (w, w^1) share the A M-tile -> A L2-shared within the XCD.
    const int bid = blockIdx.x;
    const int xcd = bid & 7, rank = bid >> 3;
    const int w = (xcd < GEMM_XR) ? xcd * (GEMM_XQ + 1) + rank
                                  : GEMM_XR * (GEMM_XQ + 1) + (xcd - GEMM_XR) * GEMM_XQ + rank;
    const int bm = (w >> 1) * 64;
    const int bn = (w & 1) * 256;

    const int t = threadIdx.x;
    const int wv = t >> 6, lane = t & 63;
    const int wm = wv & 1, wn = wv >> 1;     // wm: M-half, wn: head within the 256-col half
    const int lm = lane & 15, lk = lane >> 4;

    float4v acc[2][8];
    #pragma unroll
    for (int i = 0; i < 2; i++)
        #pragma unroll
        for (int j = 0; j < 8; j++) acc[i][j] = (float4v){0.f, 0.f, 0.f, 0.f};

    const int srow = t >> 2;                                 // 0..63
    const int sk   = ((t & 3) ^ ((t >> 3) & 3)) * 8;         // pre-swizzled global k-slot
    const int swr  = (lk ^ ((lm >> 1) & 3)) * 8;             // swizzled read slot

#define GEMM_STAGE(buf, kof)                                                                   \
    {                                                                                          \
        const unsigned short* gA = A + (size_t)(bm + srow) * IN_CH + (kof) + sk;               \
        __builtin_amdgcn_global_load_lds((const __attribute__((address_space(1))) void*)gA,    \
            (__attribute__((address_space(3))) void*)&As[buf][t * 8], 16, 0, 0);               \
        _Pragma("unroll")                                                                      \
        for (int q = 0; q < 4; q++) {                                                          \
            const unsigned short* gB = Bt + (size_t)(bn + q * 64 + srow) * IN_CH + (kof) + sk; \
            __builtin_amdgcn_global_load_lds((const __attribute__((address_space(1))) void*)gB,\
                (__attribute__((address_space(3))) void*)&Bs[buf][q * 2048 + t * 8], 16, 0, 0);\
        }                                                                                      \
    }

    GEMM_STAGE(0, 0);
    #pragma unroll
    for (int kk = 0; kk < 16; ++kk) {
        const int cur = kk & 1;
        if (kk < 15) {
            GEMM_STAGE(cur ^ 1, (kk + 1) * 32);                // prefetch next tile
            asm volatile("s_waitcnt vmcnt(5)" ::: "memory");   // this tile's 5 loads done
        } else {
            asm volatile("s_waitcnt vmcnt(0)" ::: "memory");
        }
        __builtin_amdgcn_s_barrier();
        __builtin_amdgcn_sched_barrier(0);                     // no ds_read hoist above barrier

        short8 af[2], bf[8];
        #pragma unroll
        for (int i = 0; i < 2; i++)
            af[i] = *(const short8*)&As[cur][(wm * 32 + i * 16 + lm) * 32 + swr];
        #pragma unroll
        for (int j = 0; j < 8; j++)
            bf[j] = *(const short8*)&Bs[cur][(wn * 128 + j * 16 + lm) * 32 + swr];
        #pragma unroll
        for (int i = 0; i < 2; i++)
            #pragma unroll
            for (int j = 0; j < 8; j++)
                acc[i][j] = __builtin_amdgcn_mfma_f32_16x16x32_bf16(af[i], bf[j], acc[i][j], 0, 0, 0);

        __builtin_amdgcn_sched_barrier(0);                     // reads stay inside the phase
        __builtin_amdgcn_s_barrier();
    }
#undef GEMM_STAGE

    // C store (flat [row][col] bf16)
    #pragma unroll
    for (int i = 0; i < 2; i++) {
        #pragma unroll
        for (int r = 0; r < 4; r++) {
            int row = bm + wm * 32 + i * 16 + lk * 4 + r;
            if (row < N_NODES) {
                #pragma unroll
                for (int j = 0; j < 8; j++) {
                    int col = bn + wn * 128 + j * 16 + lm;
                    Cb[(size_t)row * HC + col] = f2bf(acc[i][j][r]);
                }
            }
        }
    }

    // ---- attention-half epilogue: this wave owns full head h -> in-wave reduce only ----
    const int h = (bn >> 7) + wn;
    float as_w[8], ad_w[8];
    #pragma unroll
    for (int j = 0; j < 8; j++) {
        int col = h * 128 + j * 16 + lm;           // flat index into [4][128] att arrays
        as_w[j] = att_s[col];
        ad_w[j] = att_d[col];
    }
    float ps[2][4], pd[2][4];
    #pragma unroll
    for (int i = 0; i < 2; i++)
        #pragma unroll
        for (int r = 0; r < 4; r++) {
            float s = 0.f, d = 0.f;
            #pragma unroll
            for (int j = 0; j < 8; j++) { s += acc[i][j][r] * as_w[j]; d += acc[i][j][r] * ad_w[j]; }
            ps[i][r] = s; pd[i][r] = d;
        }
    #pragma unroll
    for (int off = 1; off < 16; off <<= 1) {
        #pragma unroll
        for (int i = 0; i < 2; i++)
            #pragma unroll
            for (int r = 0; r < 4; r++) {
                ps[i][r] += __shfl_xor(ps[i][r], off, 64);
                pd[i][r] += __shfl_xor(pd[i][r], off, 64);
            }
    }
    if (lm == 0) {
        #pragma unroll
        for (int i = 0; i < 2; i++)
            #pragma unroll
            for (int r = 0; r < 4; r++) {
                int row = bm + wm * 32 + i * 16 + lk * 4 + r;
                if (row < N_NODES) {
                    a_s[row * 4 + h] = ps[i][r];
                    a_d[row * 4 + h] = pd[i][r];
                }
            }
    }
}

// ---------------- K3: exclusive scan counts -> offsets (single block) ----------------
__global__ __launch_bounds__(1024) void scan_kernel(const int* __restrict__ counts,
                                                    int* __restrict__ offsets) {
    const int CHUNK = 20;                 // 1024*20 = 20480 >= N_NODES
    int tid = threadIdx.x;
    int base = tid * CHUNK;
    int c[CHUNK];
    #pragma unroll
    for (int k = 0; k < CHUNK; k++) {
        int i = base + k;
        c[k] = (i < N_NODES) ? counts[i] : 0;
    }
    int pre[CHUNK];
    int sum = 0;
    #pragma unroll
    for (int k = 0; k < CHUNK; k++) { pre[k] = sum; sum += c[k]; }

    int lane = tid & 63, wvv = tid >> 6;
    int s = sum;
    #pragma unroll
    for (int off = 1; off < 64; off <<= 1) {
        int u = __shfl_up(s, off, 64);
        if (lane >= off) s += u;
    }
    __shared__ int wsum[16];
    if (lane == 63) wsum[wvv] = s;
    __syncthreads();
    if (tid < 16) {
        int u = wsum[tid];
        #pragma unroll
        for (int off = 1; off < 16; off <<= 1) {
            int w = __shfl_up(u, off, 64);
            if (tid >= off) u += w;
        }
        wsum[tid] = u;
    }
    __syncthreads();
    int wbase = (wvv == 0) ? 0 : wsum[wvv - 1];
    int excl = wbase + s - sum;
    #pragma unroll
    for (int k = 0; k < CHUNK; k++) {
        int i = base + k;
        if (i < N_NODES) offsets[i] = excl + pre[k];
    }
    if (tid == 1023) offsets[N_NODES] = wbase + s;
}

// ---------------- K4: scatter + per-edge weights (no atomics — epos precomputed) ----------------
__global__ __launch_bounds__(256) void scatterw_kernel(const void* __restrict__ ei,
                                                       const int* __restrict__ offsets,
                                                       const int* __restrict__ epos,
                                                       int* __restrict__ sorted_src,
                                                       const float* __restrict__ a_s,
                                                       const float* __restrict__ a_d,
                                                       float* __restrict__ edge_w) {
    int is64 = detect_is64((const int*)ei);
    int e = blockIdx.x * 256 + threadIdx.x;
    if (e < N_EDGES) {
        int dst = edge_at(ei, is64, (long long)N_EDGES + e);
        int src = edge_at(ei, is64, e);
        int pos = offsets[dst] + epos[e];
        sorted_src[pos] = src;
        float4 as4 = *(const float4*)&a_s[src * 4];
        float4 ad4 = *(const float4*)&a_d[dst * 4];
        float4 w;
        w.x = __expf(leaky(as4.x + ad4.x));
        w.y = __expf(leaky(as4.y + ad4.y));
        w.z = __expf(leaky(as4.z + ad4.z));
        w.w = __expf(leaky(as4.w + ad4.w));
        *(float4*)&edge_w[(size_t)pos * 4] = w;
    }
}

// ---------------- segment softmax + weighted gather (2 waves/node, pipelined) ----------------
// Index/weight loads for chunk i+1 are prefetched before chunk i's row loads are consumed,
// breaking the 2-level dependent-load chain. Tail handled by clamped index + zero weight
// (no divergent tail loop). No max subtraction (logits bounded; algebraically identical).
__global__ __launch_bounds__(256) void gather_kernel(const unsigned short* __restrict__ xlb,
                                                     const float* __restrict__ a_s,
                                                     const float* __restrict__ a_d,
                                                     const int* __restrict__ offsets,
                                                     const int* __restrict__ sorted_src,
                                                     const float* __restrict__ edge_w,
                                                     const float* __restrict__ bias,
                                                     float* __restrict__ out) {
    __shared__ float cl[2][64][9];
    int wv = threadIdx.x >> 6;
    int nib = wv >> 1;                  // node in block (0..1)
    int sub = wv & 1;                   // which half-wave of the node
    int node = blockIdx.x * 2 + nib;    // grid = N_NODES/2
    int lane = threadIdx.x & 63;
    int hd = lane >> 4;
    int beg = offsets[node], end = offsets[node + 1];

    const unsigned short* xrow = xlb + lane * 8;
    float acc[8] = {0, 0, 0, 0, 0, 0, 0, 0};
    float denom = 0.f;

    // preload first chunk's indices+weights (clamped index, OOB slots zero-weighted)
    int c0 = beg + sub * 4;
    int s0 = 0, s1 = 0, s2 = 0, s3 = 0;
    float w0 = 0.f, w1 = 0.f, w2 = 0.f, w3 = 0.f;
    if (c0 < end) {
        int lim = end - 1;
        int i1 = c0 + 1 > lim ? lim : c0 + 1;
        int i2 = c0 + 2 > lim ? lim : c0 + 2;
        int i3 = c0 + 3 > lim ? lim : c0 + 3;
        s0 = sorted_src[c0]; s1 = sorted_src[i1]; s2 = sorted_src[i2]; s3 = sorted_src[i3];
        float4 t0 = *(const float4*)&edge_w[(size_t)c0 * 4];
        float4 t1 = *(const float4*)&edge_w[(size_t)i1 * 4];
        float4 t2 = *(const float4*)&edge_w[(size_t)i2 * 4];
        float4 t3 = *(const float4*)&edge_w[(size_t)i3 * 4];
        w0 = sel_head(t0, hd);
        w1 = (c0 + 1 < end) ? sel_head(t1, hd) : 0.f;
        w2 = (c0 + 2 < end) ? sel_head(t2, hd) : 0.f;
        w3 = (c0 + 3 < end) ? sel_head(t3, hd) : 0.f;
    }

    if (sub == 0) {   // self-loop
        float4 as4 = *(const float4*)&a_s[node * 4];
        float4 ad4 = *(const float4*)&a_d[node * 4];
        float4 ws;
        ws.x = __expf(leaky(as4.x + ad4.x));
        ws.y = __expf(leaky(as4.y + ad4.y));
        ws.z = __expf(leaky(as4.z + ad4.z));
        ws.w = __expf(leaky(as4.w + ad4.w));
        float w = sel_head(ws, hd);
        denom = w;
        uint4 r = *(const uint4*)(xrow + (size_t)node * HC);
        float f[8];
        bf8_decode(r, f);
        #pragma unroll
        for (int k = 0; k < 8; k++) acc[k] = w * f[k];
    }

    for (; c0 < end; c0 += 8) {
        // issue row loads for current chunk
        uint4 r0 = *(const uint4*)(xrow + (size_t)s0 * HC);
        uint4 r1 = *(const uint4*)(xrow + (size_t)s1 * HC);
        uint4 r2 = *(const uint4*)(xrow + (size_t)s2 * HC);
        uint4 r3 = *(const uint4*)(xrow + (size_t)s3 * HC);

        // prefetch next chunk's indices+weights (overlaps row-load latency)
        int c1 = c0 + 8;
        int n0 = 0, n1 = 0, n2 = 0, n3 = 0;
        float v0 = 0.f, v1 = 0.f, v2 = 0.f, v3 = 0.f;
        if (c1 < end) {
            int lim = end - 1;
            int i1 = c1 + 1 > lim ? lim : c1 + 1;
            int i2 = c1 + 2 > lim ? lim : c1 + 2;
            int i3 = c1 + 3 > lim ? lim : c1 + 3;
            n0 = sorted_src[c1]; n1 = sorted_src[i1]; n2 = sorted_src[i2]; n3 = sorted_src[i3];
            float4 t0 = *(const float4*)&edge_w[(size_t)c1 * 4];
            float4 t1 = *(const float4*)&edge_w[(size_t)i1 * 4];
            float4 t2 = *(const float4*)&edge_w[(size_t)i2 * 4];
            float4 t3 = *(const float4*)&edge_w[(size_t)i3 * 4];
            v0 = sel_head(t0, hd);
            v1 = (c1 + 1 < end) ? sel_head(t1, hd) : 0.f;
            v2 = (c1 + 2 < end) ? sel_head(t2, hd) : 0.f;
            v3 = (c1 + 3 < end) ? sel_head(t3, hd) : 0.f;
        }

        denom += (w0 + w1) + (w2 + w3);
        float f0[8], f1[8], f2[8], f3[8];
        bf8_decode(r0, f0);
        bf8_decode(r1, f1);
        bf8_decode(r2, f2);
        bf8_decode(r3, f3);
        #pragma unroll
        for (int k = 0; k < 8; k++)
            acc[k] += (w0 * f0[k] + w1 * f1[k]) + (w2 * f2[k] + w3 * f3[k]);

        s0 = n0; s1 = n1; s2 = n2; s3 = n3;
        w0 = v0; w1 = v1; w2 = v2; w3 = v3;
    }

    if (sub == 1) {
        #pragma unroll
        for (int k = 0; k < 8; k++) cl[nib][lane][k] = acc[k];
        cl[nib][lane][8] = denom;
    }
    __syncthreads();
    if (sub == 0) {
        #pragma unroll
        for (int k = 0; k < 8; k++) acc[k] += cl[nib][lane][k];
        denom += cl[nib][lane][8];

        float rd = 0.25f / (denom + 1e-16f);   // fold head-mean into normalize
        float v[8];
        #pragma unroll
        for (int k = 0; k < 8; k++) {
            float t = acc[k] * rd;
            t += __shfl_xor(t, 16, 64);
            t += __shfl_xor(t, 32, 64);
            v[k] = t;
        }
        if (hd == 0) {
            float4 b0 = *(const float4*)&bias[lane * 8];
            float4 b1 = *(const float4*)&bias[lane * 8 + 4];
            float o[8];
            o[0] = v[0] + b0.x; o[1] = v[1] + b0.y; o[2] = v[2] + b0.z; o[3] = v[3] + b0.w;
            o[4] = v[4] + b1.x; o[5] = v[5] + b1.y; o[6] = v[6] + b1.z; o[7] = v[7] + b1.w;
            #pragma unroll
            for (int k = 0; k < 8; k++) o[k] = o[k] > 0.f ? o[k] : expm1f(o[k]);
            *(float4*)&out[(size_t)node * OUT_CH + lane * 8]     = make_float4(o[0], o[1], o[2], o[3]);
            *(float4*)&out[(size_t)node * OUT_CH + lane * 8 + 4] = make_float4(o[4], o[5], o[6], o[7]);
        }
    }
}

// ---------------- launch ----------------
extern "C" void kernel_launch(void* const* d_in, const int* in_sizes, int n_in,
                              void* d_out, int out_size, void* d_ws, size_t ws_size,
                              hipStream_t stream) {
    const float* x       = (const float*)d_in[0];
    const float* W       = (const float*)d_in[1];
    const float* att_src = (const float*)d_in[2];
    const float* att_dst = (const float*)d_in[3];
    const float* bias    = (const float*)d_in[4];
    const void*  ei      = d_in[5];
    float* out = (float*)d_out;

    char* ws = (char*)d_ws;
    size_t off = 0;
    unsigned short* xlb = (unsigned short*)(ws + off); off += (size_t)N_PAD * HC * sizeof(unsigned short);
    float* a_s     = (float*)(ws + off); off += (size_t)N_NODES * HEADS * sizeof(float);
    float* a_d     = (float*)(ws + off); off += (size_t)N_NODES * HEADS * sizeof(float);
    int* counts    = (int*)(ws + off);   off += (size_t)N_NODES * sizeof(int);
    int* offsets   = (int*)(ws + off);   off += (size_t)(N_NODES + 1) * sizeof(int);
    off = (off + 15) & ~(size_t)15;
    int* epos      = (int*)(ws + off);   off += (size_t)N_EDGES * sizeof(int);
    int* sorted_src = (int*)(ws + off);  off += (size_t)N_EDGES * sizeof(int);
    off = (off + 15) & ~(size_t)15;
    float* edge_w  = (float*)(ws + off); off += (size_t)N_EDGES * HEADS * sizeof(float);
    unsigned short* xb = (unsigned short*)(ws + off); off += (size_t)N_PAD * IN_CH * sizeof(unsigned short);
    unsigned short* Wt = (unsigned short*)(ws + off); off += (size_t)IN_CH * HC * sizeof(unsigned short);

    hipMemsetAsync(counts, 0, N_NODES * sizeof(int), stream);
    fusedA_kernel<<<CVX_BLOCKS + CVW_BLOCKS + CNT_BLOCKS, 256, 0, stream>>>(x, W, xb, Wt, ei, counts, epos);
    gemm_kernel<<<GEMM_WGS, 256, 0, stream>>>(xb, Wt, xlb, att_src, att_dst, a_s, a_d);
    scan_kernel<<<1, 1024, 0, stream>>>(counts, offsets);
    scatterw_kernel<<<(N_EDGES + 255) / 256, 256, 0, stream>>>(ei, offsets, epos, sorted_src, a_s, a_d, edge_w);
    gather_kernel<<<N_NODES / 2, 256, 0, stream>>>(xlb, a_s, a_d, offsets, sorted_src, edge_w, bias, out);
}